// Round 1
// 817.285 us; speedup vs baseline: 1.0570x; 1.0570x over previous
//
#include <hip/hip_runtime.h>
#include <hip/hip_bf16.h>
#include <math.h>

typedef unsigned short u16;
typedef __attribute__((ext_vector_type(8))) short short8;   // 8 bf16 (4 VGPRs)
typedef __attribute__((ext_vector_type(4))) float f32x4;    // MFMA C/D frag

// Problem constants: B=8, N=2048, D=DC=1024, K_centers=4, M = B*N = 16384.
//
// R4 algebra (no fus2, no tc2, no tc1 as separate GEMMs):
//   h1    = gelu(ring_gather(x) @ fr_w1 + fr_b1)                 [240 GF]
//   joint1 over h1 (Nout=2048, K=1024):                          [68.7 GF]
//     x_ring = h1 @ fr_w2 + fr_b2          (f32 + bf16 copies)
//     h2     = gelu(h1 @ M2 + c2),  M2 = fr_w2@tc_w1 (precomputed GEMM),
//                                   c2 = fr_b2@tc_w1 + tc_b1
//   w = softmax(h2 @ S^T + bc),  S = centers@tc_w2^T (folded tc2) [small]
//   joint2 over x_ring_bf16 (Nout=2048, K=1024):                 [68.7 GF]
//     gate = sigmoid(x_ring@g_w_top  + w@G2 + g_b)   G2 = centers@g_w_bot
//     fch  = gelu  (x_ring@fc_w1_top + w@F2 + fc_b1) F2 = centers@fc_w1_bot
//   out = gate*(fch @ fc_w2 + fc_b2) + (1-gate)*x_ring           [34 GF]
//
// R5: main GEMMs moved from 128x128/2-barrier (m97-class, ~730 TF measured,
// MfmaUtil 32%) to a 256x256 deep-pipelined schedule (T2+T3+T4+T5):
//   BK=32, ring of 4 LDS buffers (128 KB dynamic), 8 waves (2x4),
//   2 phases/K-step {ds_read || cp16-prefetch(+3 steps) ; s_barrier ;
//   lgkmcnt(0) ; setprio(1) ; 16 MFMA ; setprio(0) ; s_barrier},
//   vmcnt(8) once per K-step (counted, never drains to 0 in main loop).

__device__ __forceinline__ float bf2f(u16 b) {
  return __uint_as_float(((unsigned int)b) << 16);
}
__device__ __forceinline__ u16 f2bf(float f) {
  unsigned int u = __float_as_uint(f);
  u += 0x7FFFu + ((u >> 16) & 1u);   // round-to-nearest-even (finite inputs)
  return (u16)(u >> 16);
}
__device__ __forceinline__ float gelu_exact(float x) {
  return 0.5f * x * (1.0f + erff(x * 0.70710678118654752f));
}

// async 16B/lane global->LDS. LDS dest is wave-uniform base + lane*16.
__device__ __forceinline__ void cp16(const void* g, void* l) {
  __builtin_amdgcn_global_load_lds(
      (const __attribute__((address_space(1))) unsigned int*)g,
      (__attribute__((address_space(3))) unsigned int*)l, 16, 0, 0);
}

// ---------------------------------------------------------------------------
// gemm256: C[M,Nout] = A[M,K](bf16) @ Wt[Nout,K]^T(bf16)
// 256x256 tile, BK=32, ring-4 LDS double-buffer, 512 threads (8 waves 2x4),
// per-wave 128x64 out = acc[8][4] of 16x16x32 MFMA.
//
// LDS layout per buffer (A 16KB then B 16KB): paired-row swizzle.
//   Superrow sr = row>>1 (128B). Slot qq in [0,8) of 16B. Content of
//   (sr,qq): row = sr*2 + (qqp>>2), kquad = qqp&3, qqp = qq ^ (sr&7).
//   Writes are linear (wave-uniform base + lane*16, m173: source is
//   pre-inverse-swizzled); reads use qq = ((row&1)*4 + kq) ^ (sr&7).
//   Bank check: 64-lane b128 read puts exactly 2 lanes on each 16B slot
//   group => even 8 words/bank (conflict-free aggregate).
//
// vmcnt ledger (4 loads/step/thread: A=2 + B=2, issued 3 steps ahead):
//   prologue stages steps 0,1,2 (12 loads), vmcnt(8) => step0 landed.
//   step s phase a issues A(s+3), phase b issues B(s+3) then vmcnt(8):
//   confirms all but newest 8 = everything through step s+1. Tail clamps
//   the *source* to nt-1 (dest ring slot never read again) so the issue
//   count stays uniform and the counted wait stays valid.
// ---------------------------------------------------------------------------
template <int MODE, bool GATHER>
__global__ __launch_bounds__(512) void gemm256(
    const u16* __restrict__ A, int lda, const u16* __restrict__ Wt, int K,
    const float* __restrict__ bias, const float* __restrict__ bias2,
    void* __restrict__ out0, int ldo0, void* __restrict__ out1,
    void* __restrict__ out2, const float* __restrict__ p0,
    const float* __restrict__ p1, const float* __restrict__ p2) {
  extern __shared__ __align__(16) char sm[];   // 4 bufs * 32 KB = 128 KB
  const int tid = threadIdx.x;
  const int lane = tid & 63;
  const int wave = tid >> 6;     // 0..7
  const int wm = wave >> 2;      // wave row in 2x4
  const int wn = wave & 3;       // wave col

  // ---- XCD-aware block swizzle (gridDim.y divisible by 8) ----
  const unsigned linear = blockIdx.y * gridDim.x + blockIdx.x;
  const unsigned xcd = linear & 7u;
  const unsigned pos = linear >> 3;
  const unsigned bx = pos % gridDim.x;
  const unsigned by = xcd * (gridDim.y >> 3) + pos / gridDim.x;
  const int m0 = by * 256;
  const int n0 = bx * 256;

  // staging (write-side) lane constants: lane covers (sr = chunk*8 + sl, qq)
  const int sl = lane >> 3;           // 0..7 superrow within 1KB chunk
  const int qqs = (lane & 7) ^ sl;    // pre-inverse-swizzled content slot
  const int rowoff = sl * 2 + (qqs >> 2);  // row within 16-row chunk
  const int colq = qqs & 3;                // k-quad (8 bf16) within BK=32

  // ds_read (read-side) lane constants
  const int r16 = lane & 15, q4 = lane >> 4;
  const int qqr = (((r16 & 1) << 2) | q4) ^ (r16 >> 1);
  const int laneA = wm * 8192 + (r16 >> 1) * 128 + qqr * 16;  // bytes
  const int laneB = wn * 4096 + (r16 >> 1) * 128 + qqr * 16;

  const int nt = K >> 5;   // K/32 steps

  f32x4 acc[8][4];
#pragma unroll
  for (int i = 0; i < 8; i++)
#pragma unroll
    for (int j = 0; j < 4; j++) acc[i][j] = (f32x4){0.f, 0.f, 0.f, 0.f};

  auto stage_A = [&](int sdst, int ssrc) {
#pragma unroll
    for (int i = 0; i < 2; i++) {
      const int chunk = wave + i * 8;        // 0..15 (1KB each)
      const int row = chunk * 16 + rowoff;   // 0..255 tile row
      long gofs;
      if (GATHER) {
        const int kg = ssrc * 32 + colq * 8;  // global k (seg-uniform per step)
        const int seg = kg >> 10;
        int shift;
        switch (seg) {
          case 0: shift = 1; break;
          case 1: shift = -1; break;
          case 2: shift = 0; break;
          case 3: shift = 2; break;
          case 4: shift = -2; break;
          case 5: shift = 4; break;
          default: shift = -4; break;
        }
        const int m = m0 + row;
        const int b = m >> 11;                 // N = 2048 = 2^11
        const int nsrc = ((m & 2047) - shift) & 2047;
        gofs = (long)((b << 11) | nsrc) * 1024 + (kg & 1023);
      } else {
        gofs = (long)(m0 + row) * lda + ssrc * 32 + colq * 8;
      }
      cp16(A + gofs, sm + (sdst & 3) * 32768 + chunk * 1024);
    }
  };
  auto stage_B = [&](int sdst, int ssrc) {
#pragma unroll
    for (int i = 0; i < 2; i++) {
      const int chunk = wave + i * 8;
      const int row = chunk * 16 + rowoff;
      const long gofs = (long)(n0 + row) * K + ssrc * 32 + colq * 8;
      cp16(Wt + gofs, sm + (sdst & 3) * 32768 + 16384 + chunk * 1024);
    }
  };

  // ---- prologue: stage steps 0,1,2; confirm step 0 (oldest 4 of 12) ----
  stage_A(0, 0); stage_B(0, 0);
  stage_A(1, 1); stage_B(1, 1);
  stage_A(2, 2); stage_B(2, 2);
  asm volatile("s_waitcnt vmcnt(8)" ::: "memory");
  __builtin_amdgcn_s_barrier();

  for (int s = 0; s < nt; ++s) {
    const int s3 = (s + 3 < nt) ? s + 3 : nt - 1;  // clamped source step
    const char* abase = sm + (s & 3) * 32768;
    short8 af[4], bf[4];

    // ---- phase a: m-frags 0..3 ----
#pragma unroll
    for (int ni = 0; ni < 4; ni++)
      bf[ni] = *(const short8*)(abase + 16384 + laneB + ni * 1024);
#pragma unroll
    for (int mi = 0; mi < 4; mi++)
      af[mi] = *(const short8*)(abase + laneA + mi * 1024);
    stage_A(s + 3, s3);
    __builtin_amdgcn_s_barrier();
    asm volatile("s_waitcnt lgkmcnt(0)" ::: "memory");
    __builtin_amdgcn_sched_barrier(0);
    __builtin_amdgcn_s_setprio(1);
#pragma unroll
    for (int mi = 0; mi < 4; mi++)
#pragma unroll
      for (int ni = 0; ni < 4; ni++)
        acc[mi][ni] = __builtin_amdgcn_mfma_f32_16x16x32_bf16(
            af[mi], bf[ni], acc[mi][ni], 0, 0, 0);
    __builtin_amdgcn_s_setprio(0);
    __builtin_amdgcn_s_barrier();

    // ---- phase b: m-frags 4..7 (reuse bf) ----
#pragma unroll
    for (int mi = 0; mi < 4; mi++)
      af[mi] = *(const short8*)(abase + laneA + 4096 + mi * 1024);
    stage_B(s + 3, s3);
    asm volatile("s_waitcnt vmcnt(8)" ::: "memory");  // step s+1 landed
    __builtin_amdgcn_s_barrier();
    asm volatile("s_waitcnt lgkmcnt(0)" ::: "memory");
    __builtin_amdgcn_sched_barrier(0);
    __builtin_amdgcn_s_setprio(1);
#pragma unroll
    for (int mi = 0; mi < 4; mi++)
#pragma unroll
      for (int ni = 0; ni < 4; ni++)
        acc[4 + mi][ni] = __builtin_amdgcn_mfma_f32_16x16x32_bf16(
            af[mi], bf[ni], acc[4 + mi][ni], 0, 0, 0);
    __builtin_amdgcn_s_setprio(0);
    __builtin_amdgcn_s_barrier();
  }
  asm volatile("s_waitcnt vmcnt(0)" ::: "memory");  // drain tail re-stages

  // epilogue: C/D layout col = lane&15, row = (lane>>4)*4 + reg
  const int ccol = lane & 15;
  const int crow = (lane >> 4) * 4;
#pragma unroll
  for (int mi = 0; mi < 8; mi++) {
#pragma unroll
    for (int r = 0; r < 4; r++) {
      const int m = m0 + wm * 128 + mi * 16 + crow + r;
      float4 wrow;
      if (MODE == 8) wrow = *(const float4*)(p0 + (size_t)m * 4);
#pragma unroll
      for (int ni = 0; ni < 4; ni++) {
        const int n = n0 + wn * 64 + ni * 16 + ccol;
        const float v = acc[mi][ni][r];
        if (MODE == 0) {
          ((u16*)out0)[(long)m * ldo0 + n] = f2bf(gelu_exact(v + bias[n]));
        } else if (MODE == 4) {
          const float g = p0[(long)m * 1024 + n];
          const float xr = p1[(long)m * 1024 + n];
          ((float*)out0)[(long)m * ldo0 + n] =
              g * (v + bias[n]) + (1.0f - g) * xr;
        } else if (MODE == 6) {
          ((u16*)out0)[(long)m * ldo0 + n] = f2bf(v);
        } else if (MODE == 7) {
          if (n < 1024) {
            const float s = v + bias[n];
            ((float*)out1)[(long)m * 1024 + n] = s;
            ((u16*)out0)[(long)m * 1024 + n] = f2bf(s);
          } else {
            const int nn = n - 1024;
            ((u16*)out2)[(long)m * 1024 + nn] = f2bf(gelu_exact(v + bias2[nn]));
          }
        } else if (MODE == 8) {
          if (n < 1024) {
            const float4 g2 = *(const float4*)(p1 + (size_t)n * 4);
            const float s = v + bias[n] + wrow.x * g2.x + wrow.y * g2.y +
                            wrow.z * g2.z + wrow.w * g2.w;
            ((float*)out0)[(long)m * 1024 + n] = 1.0f / (1.0f + expf(-s));
          } else {
            const int nn = n - 1024;
            const float4 f2 = *(const float4*)(p2 + (size_t)nn * 4);
            const float s = v + bias2[nn] + wrow.x * f2.x + wrow.y * f2.y +
                            wrow.z * f2.z + wrow.w * f2.w;
            ((u16*)out1)[(long)m * 1024 + nn] = f2bf(gelu_exact(s));
          }
        }
      }
    }
  }
}

// ---------------------------------------------------------------------------
// gemm128 (m97-class, kept only for the small M2 precompute: M=1024, MODE 6)
// ---------------------------------------------------------------------------
template <int MODE, bool GATHER>
__global__ __launch_bounds__(256) void gemm128(
    const u16* __restrict__ A, int lda, const u16* __restrict__ Wt, int K,
    const float* __restrict__ bias, const float* __restrict__ bias2,
    void* __restrict__ out0, int ldo0, void* __restrict__ out1,
    void* __restrict__ out2, const float* __restrict__ p0,
    const float* __restrict__ p1, const float* __restrict__ p2) {
  __shared__ __align__(16) u16 As[128 * 64];
  __shared__ __align__(16) u16 Bs[128 * 64];

  const int tid = threadIdx.x;
  const int lane = tid & 63;
  const int wave = tid >> 6;     // 0..3
  const int wm = wave >> 1;      // wave row in 2x2
  const int wn = wave & 1;       // wave col

  const unsigned linear = blockIdx.y * gridDim.x + blockIdx.x;
  const unsigned xcd = linear & 7u;
  const unsigned pos = linear >> 3;
  const unsigned bx = pos % gridDim.x;
  const unsigned by = xcd * (gridDim.y >> 3) + pos / gridDim.x;
  const int m0 = by * 128;
  const int n0 = bx * 128;

  const int srow = lane >> 3;    // 0..7: row within an 8-row staging chunk
  const int sq = lane & 7;       // quad (16B) within a 128B row
  const int sqs = sq ^ srow;     // swizzled global quad

  f32x4 acc[4][4];
#pragma unroll
  for (int i = 0; i < 4; i++)
#pragma unroll
    for (int j = 0; j < 4; j++) acc[i][j] = (f32x4){0.f, 0.f, 0.f, 0.f};

  for (int k0 = 0; k0 < K; k0 += 64) {
#pragma unroll
    for (int i = 0; i < 4; i++) {
      const int rloc = wave * 32 + i * 8 + srow;   // 0..127
      long gofs;
      if (GATHER) {
        const int seg = k0 >> 10;
        int shift;
        switch (seg) {
          case 0: shift = 1; break;
          case 1: shift = -1; break;
          case 2: shift = 0; break;
          case 3: shift = 2; break;
          case 4: shift = -2; break;
          case 5: shift = 4; break;
          default: shift = -4; break;
        }
        const int m = m0 + rloc;
        const int b = m >> 11;
        const int nsrc = ((m & 2047) - shift) & 2047;
        gofs = (long)((b << 11) | nsrc) * 1024 + (k0 & 1023) + sqs * 8;
      } else {
        gofs = (long)(m0 + rloc) * lda + k0 + sqs * 8;
      }
      cp16(A + gofs, &As[(wave * 32 + i * 8) * 64]);
    }
#pragma unroll
    for (int i = 0; i < 4; i++) {
      const int rloc = wave * 32 + i * 8 + srow;
      const long gofs = (long)(n0 + rloc) * K + k0 + sqs * 8;
      cp16(Wt + gofs, &Bs[(wave * 32 + i * 8) * 64]);
    }
    __syncthreads();

    const int q4 = lane >> 4;     // 0..3
    const int r16 = lane & 15;
#pragma unroll
    for (int kk = 0; kk < 2; kk++) {
      short8 af[4], bf[4];
#pragma unroll
      for (int mi = 0; mi < 4; mi++) {
        const int row = wm * 64 + mi * 16 + r16;
        const int q = (kk * 4 + q4) ^ (row & 7);
        af[mi] = *(const short8*)&As[row * 64 + q * 8];
      }
#pragma unroll
      for (int ni = 0; ni < 4; ni++) {
        const int row = wn * 64 + ni * 16 + r16;
        const int q = (kk * 4 + q4) ^ (row & 7);
        bf[ni] = *(const short8*)&Bs[row * 64 + q * 8];
      }
#pragma unroll
      for (int mi = 0; mi < 4; mi++)
#pragma unroll
        for (int ni = 0; ni < 4; ni++)
          acc[mi][ni] = __builtin_amdgcn_mfma_f32_16x16x32_bf16(
              af[mi], bf[ni], acc[mi][ni], 0, 0, 0);
    }
    __syncthreads();
  }

  const int ccol = lane & 15;
  const int crow = (lane >> 4) * 4;
#pragma unroll
  for (int mi = 0; mi < 4; mi++) {
#pragma unroll
    for (int r = 0; r < 4; r++) {
      const int m = m0 + wm * 64 + mi * 16 + crow + r;
#pragma unroll
      for (int ni = 0; ni < 4; ni++) {
        const int n = n0 + wn * 64 + ni * 16 + ccol;
        const float v = acc[mi][ni][r];
        if (MODE == 6) {
          ((u16*)out0)[(long)m * ldo0 + n] = f2bf(v);
        }
      }
    }
  }
}

// fp32 -> bf16 cast, 4 elems/thread
__global__ __launch_bounds__(256) void cast_bf16(const float* __restrict__ in,
                                                 u16* __restrict__ out, int n4) {
  const long i = (long)blockIdx.x * 256 + threadIdx.x;
  if (i < n4) {
    const float4 v = ((const float4*)in)[i];
    ushort4 o;
    o.x = f2bf(v.x); o.y = f2bf(v.y); o.z = f2bf(v.z); o.w = f2bf(v.w);
    ((ushort4*)out)[i] = o;
  }
}

// W[K,N] fp32 -> Wt[N,K] bf16, 32x32 LDS tile transpose. K = OUT row length.
__global__ __launch_bounds__(256) void transp_bf16(const float* __restrict__ in,
                                                   u16* __restrict__ out, int K,
                                                   int N) {
  __shared__ float tile[32][33];
  const int tx = threadIdx.x & 31;
  const int ty = threadIdx.x >> 5;  // 0..7
  const long r0 = (long)blockIdx.y * 32;
  const long c0 = (long)blockIdx.x * 32;
#pragma unroll
  for (int r = 0; r < 4; r++)
    tile[ty + r * 8][tx] = in[(r0 + ty + r * 8) * N + c0 + tx];
  __syncthreads();
#pragma unroll
  for (int r = 0; r < 4; r++)
    out[(c0 + ty + r * 8) * K + r0 + tx] = f2bf(tile[tx][ty + r * 8]);
}

// All small precomputed folds in one launch (769 blocks, 4 waves each)
__global__ __launch_bounds__(256) void fold_all(
    const u16* __restrict__ GbT, const u16* __restrict__ FbT,
    const u16* __restrict__ Wt3, const float* __restrict__ centers,
    const float* __restrict__ fr_b2, const float* __restrict__ tc_b1,
    const float* __restrict__ tc_w2, const float* __restrict__ tc_b2,
    float* __restrict__ G2T, float* __restrict__ F2T, float* __restrict__ c2,
    float* __restrict__ S, float* __restrict__ bc) {
  const int b = blockIdx.x;
  const int wave = threadIdx.x >> 6, lane = threadIdx.x & 63;
  if (b < 256) {
    const int n = b * 4 + wave;
    float g[4] = {0.f, 0.f, 0.f, 0.f}, f[4] = {0.f, 0.f, 0.f, 0.f};
#pragma unroll
    for (int p = 0; p < 2; p++) {
      const int base = p * 512 + lane * 8;
      const short8 gv = *(const short8*)(GbT + (long)n * 1024 + base);
      const short8 fv = *(const short8*)(FbT + (long)n * 1024 + base);
#pragma unroll
      for (int e = 0; e < 8; e++) {
        const float ge = bf2f((u16)gv[e]), fe = bf2f((u16)fv[e]);
#pragma unroll
        for (int k = 0; k < 4; k++) {
          const float c = centers[k * 1024 + base + e];
          g[k] += ge * c;
          f[k] += fe * c;
        }
      }
    }
#pragma unroll
    for (int k = 0; k < 4; k++)
#pragma unroll
      for (int off = 32; off > 0; off >>= 1) {
        g[k] += __shfl_xor(g[k], off);
        f[k] += __shfl_xor(f[k], off);
      }
    if (lane == 0) {
#pragma unroll
      for (int k = 0; k < 4; k++) {
        G2T[n * 4 + k] = g[k];
        F2T[n * 4 + k] = f[k];
      }
    }
  } else if (b < 512) {
    const int j = (b - 256) * 4 + wave;
    float s = 0.f;
#pragma unroll
    for (int p = 0; p < 2; p++) {
      const int base = p * 512 + lane * 8;
      const short8 wv = *(const short8*)(Wt3 + (long)j * 1024 + base);
#pragma unroll
      for (int e = 0; e < 8; e++) s += fr_b2[base + e] * bf2f((u16)wv[e]);
    }
#pragma unroll
    for (int off = 32; off > 0; off >>= 1) s += __shfl_xor(s, off);
    if (lane == 0) c2[j] = s + tc_b1[j];
  } else if (b < 768) {
    const int d = (b - 512) * 4 + wave;
    const float* row = tc_w2 + (long)d * 1024;
    float s0 = 0.f, s1 = 0.f, s2 = 0.f, s3 = 0.f;
    for (int e = lane; e < 1024; e += 64) {
      const float w = row[e];
      s0 += w * centers[e];
      s1 += w * centers[1024 + e];
      s2 += w * centers[2048 + e];
      s3 += w * centers[3072 + e];
    }
#pragma unroll
    for (int off = 32; off > 0; off >>= 1) {
      s0 += __shfl_xor(s0, off);
      s1 += __shfl_xor(s1, off);
      s2 += __shfl_xor(s2, off);
      s3 += __shfl_xor(s3, off);
    }
    if (lane == 0) {
      S[d] = s0; S[1024 + d] = s1; S[2048 + d] = s2; S[3072 + d] = s3;
    }
  } else {
    const int k = wave;
    float s = 0.f;
    for (int e = lane; e < 1024; e += 64) s += tc_b2[e] * centers[k * 1024 + e];
#pragma unroll
    for (int off = 32; off > 0; off >>= 1) s += __shfl_xor(s, off);
    if (lane == 0) bc[k] = s;
  }
}

// w = softmax(h2 @ S^T + bc) over 4 centers; one wave per token -> w[t][0..3]
__global__ __launch_bounds__(256) void centers_kernel(
    const u16* __restrict__ h2, const float* __restrict__ S,
    const float* __restrict__ bc, float* __restrict__ wtok) {
  const int lane = threadIdx.x & 63;
  const int wave = threadIdx.x >> 6;
  const long t = (long)blockIdx.x * 4 + wave;
  const u16* row = h2 + t * 1024;
  float d0 = 0.f, d1 = 0.f, d2 = 0.f, d3 = 0.f;
#pragma unroll
  for (int j = 0; j < 2; j++) {
    const int dbase = j * 512 + lane * 8;
    const short8 v = *(const short8*)(row + dbase);
#pragma unroll
    for (int e = 0; e < 8; e++) {
      const float x = bf2f((u16)v[e]);
      const int d = dbase + e;
      d0 += x * S[d];
      d1 += x * S[1024 + d];
      d2 += x * S[2048 + d];
      d3 += x * S[3072 + d];
    }
  }
#pragma unroll
  for (int off = 32; off > 0; off >>= 1) {
    d0 += __shfl_xor(d0, off);
    d1 += __shfl_xor(d1, off);
    d2 += __shfl_xor(d2, off);
    d3 += __shfl_xor(d3, off);
  }
  if (lane == 0) {
    d0 += bc[0]; d1 += bc[1]; d2 += bc[2]; d3 += bc[3];
    const float mx = fmaxf(fmaxf(d0, d1), fmaxf(d2, d3));
    float e0 = expf(d0 - mx), e1 = expf(d1 - mx), e2 = expf(d2 - mx),
          e3 = expf(d3 - mx);
    const float inv = 1.0f / (e0 + e1 + e2 + e3);
    *(float4*)(wtok + t * 4) = (float4){e0 * inv, e1 * inv, e2 * inv, e3 * inv};
  }
}

extern "C" void kernel_launch(void* const* d_in, const int* in_sizes, int n_in,
                              void* d_out, int out_size, void* d_ws,
                              size_t ws_size, hipStream_t stream) {
  const float* queries = (const float*)d_in[0];
  const float* fr_w1 = (const float*)d_in[1];
  const float* fr_b1 = (const float*)d_in[2];
  const float* fr_w2 = (const float*)d_in[3];
  const float* fr_b2 = (const float*)d_in[4];
  const float* tc_w1 = (const float*)d_in[5];
  const float* tc_b1 = (const float*)d_in[6];
  const float* tc_w2 = (const float*)d_in[7];
  const float* tc_b2 = (const float*)d_in[8];
  const float* centers = (const float*)d_in[9];
  const float* fc_w1 = (const float*)d_in[10];
  const float* fc_b1 = (const float*)d_in[11];
  const float* fc_w2 = (const float*)d_in[12];
  const float* fc_b2 = (const float*)d_in[13];
  const float* g_w = (const float*)d_in[14];
  const float* g_b = (const float*)d_in[15];

  char* ws = (char*)d_ws;
  u16* Wt1 = (u16*)ws; ws += (size_t)7168 * 1024 * 2;   // fr_w1^T
  u16* Wt3 = (u16*)ws; ws += (size_t)1024 * 1024 * 2;   // tc_w1^T
  u16* Wt6 = (u16*)ws; ws += (size_t)1024 * 1024 * 2;   // fc_w2^T
  u16* WtJ = (u16*)ws; ws += (size_t)2048 * 1024 * 2;   // [fr_w2^T ; M2^T]
  u16* WtG2 = (u16*)ws; ws += (size_t)2048 * 1024 * 2;  // [g_w_top^T ; fc_w1_top^T]
  u16* Fw2b = (u16*)ws; ws += (size_t)1024 * 1024 * 2;  // fr_w2 bf16 (row-major)
  u16* GbT = (u16*)ws; ws += (size_t)1024 * 1024 * 2;   // g_w_bot^T bf16
  u16* FbT = (u16*)ws; ws += (size_t)1024 * 1024 * 2;   // fc_w1_bot^T bf16
  u16* Xb = (u16*)ws;  ws += (size_t)16384 * 1024 * 2;  // bf16 queries -> h2
  u16* h1 = (u16*)ws;  ws += (size_t)16384 * 1024 * 2;  // ring hidden -> fch
  u16* xrb = (u16*)ws; ws += (size_t)16384 * 1024 * 2;  // x_ring bf16
  float* xring = (float*)ws; ws += (size_t)16384 * 1024 * 4;  // x_ring f32
  float* wtok = (float*)ws; ws += (size_t)16384 * 4 * 4;      // softmax weights
  float* S = (float*)ws; ws += (size_t)4 * 1024 * 4;
  float* G2T = (float*)ws; ws += (size_t)1024 * 4 * 4;
  float* F2T = (float*)ws; ws += (size_t)1024 * 4 * 4;
  float* c2 = (float*)ws; ws += (size_t)1024 * 4;
  float* bc = (float*)ws; ws += 16;
  float* gate = (float*)d_out;  // gate f32 in d_out (read-then-overwrite)
  float* out = (float*)d_out;

  // allow 128 KB dynamic LDS on the big-tile GEMM (host-side, capture-safe)
  static bool attr_set = false;
  if (!attr_set) {
    attr_set = true;
    (void)hipFuncSetAttribute((const void*)gemm256<0, true>,
                              hipFuncAttributeMaxDynamicSharedMemorySize,
                              131072);
    (void)hipFuncSetAttribute((const void*)gemm256<7, false>,
                              hipFuncAttributeMaxDynamicSharedMemorySize,
                              131072);
    (void)hipFuncSetAttribute((const void*)gemm256<8, false>,
                              hipFuncAttributeMaxDynamicSharedMemorySize,
                              131072);
    (void)hipFuncSetAttribute((const void*)gemm256<4, false>,
                              hipFuncAttributeMaxDynamicSharedMemorySize,
                              131072);
  }

  // --- conversions / transposes ---
  cast_bf16<<<16384, 256, 0, stream>>>(queries, Xb, 16384 * 1024 / 4);
  cast_bf16<<<1024, 256, 0, stream>>>(fr_w2, Fw2b, 1024 * 1024 / 4);
  transp_bf16<<<dim3(32, 224), 256, 0, stream>>>(fr_w1, Wt1, 7168, 1024);
  transp_bf16<<<dim3(32, 32), 256, 0, stream>>>(tc_w1, Wt3, 1024, 1024);
  transp_bf16<<<dim3(32, 32), 256, 0, stream>>>(fc_w2, Wt6, 1024, 1024);
  transp_bf16<<<dim3(32, 32), 256, 0, stream>>>(fr_w2, WtJ, 1024, 1024);
  transp_bf16<<<dim3(32, 32), 256, 0, stream>>>(g_w, WtG2, 1024, 1024);
  transp_bf16<<<dim3(32, 32), 256, 0, stream>>>(fc_w1,
                                                WtG2 + (size_t)1024 * 1024,
                                                1024, 1024);
  transp_bf16<<<dim3(32, 32), 256, 0, stream>>>(g_w + (size_t)1024 * 1024, GbT,
                                                1024, 1024);
  transp_bf16<<<dim3(32, 32), 256, 0, stream>>>(fc_w1 + (size_t)1024 * 1024,
                                                FbT, 1024, 1024);
  // --- small folds: G2T/F2T, c2, S, bc ---
  fold_all<<<769, 256, 0, stream>>>(GbT, FbT, Wt3, centers, fr_b2, tc_b1,
                                    tc_w2, tc_b2, G2T, F2T, c2, S, bc);
  // --- M2^T = (fr_w2 @ tc_w1)^T via GEMM: C[j][i] = sum_e Wt3[j][e]*Fw2b[i][e]
  gemm128<6, false><<<dim3(8, 8), 256, 0, stream>>>(
      Wt3, 1024, Fw2b, 1024, nullptr, nullptr, WtJ + (size_t)1024 * 1024, 1024,
      nullptr, nullptr, nullptr, nullptr, nullptr);

  // --- main chain (256x256 deep-pipelined GEMMs) ---
  // fr1: h1 = gelu(ring_gather(x) @ fr_w1 + fr_b1)
  gemm256<0, true><<<dim3(4, 64), 512, 131072, stream>>>(
      Xb, 0, Wt1, 7168, fr_b1, nullptr, h1, 1024, nullptr, nullptr, nullptr,
      nullptr, nullptr);
  // joint1: x_ring (f32 + bf16) and h2 in one pass over h1
  gemm256<7, false><<<dim3(8, 64), 512, 131072, stream>>>(
      h1, 1024, WtJ, 1024, fr_b2, c2, xrb, 1024, xring, Xb, nullptr, nullptr,
      nullptr);
  // w = softmax(h2 @ S^T + bc)
  centers_kernel<<<4096, 256, 0, stream>>>(Xb, S, bc, wtok);
  // joint2: gate -> d_out, fch -> h1 (w-corrections in epilogue)
  gemm256<8, false><<<dim3(8, 64), 512, 131072, stream>>>(
      xrb, 1024, WtG2, 1024, g_b, fc_b1, gate, 1024, h1, nullptr, wtok, G2T,
      F2T);
  // fc2 + final mix: out = gate*(fch @ fc_w2 + fc_b2) + (1-gate)*x_ring
  gemm256<4, false><<<dim3(4, 64), 512, 131072, stream>>>(
      h1, 1024, Wt6, 1024, fc_b2, nullptr, out, 1024, nullptr, nullptr, gate,
      xring, nullptr);
}

// Round 2
// 810.571 us; speedup vs baseline: 1.0658x; 1.0083x over previous
//
#include <hip/hip_runtime.h>
#include <hip/hip_bf16.h>
#include <math.h>

typedef unsigned short u16;
typedef __attribute__((ext_vector_type(8))) short short8;   // 8 bf16 (4 VGPRs)
typedef __attribute__((ext_vector_type(4))) float f32x4;    // MFMA C/D frag

// Problem constants: B=8, N=2048, D=DC=1024, K_centers=4, M = B*N = 16384.
//
// R4 algebra (no fus2, no tc2, no tc1 as separate GEMMs):
//   h1    = gelu(ring_gather(x) @ fr_w1 + fr_b1)                 [240 GF]
//   joint1 over h1 (Nout=2048, K=1024):                          [68.7 GF]
//     x_ring = h1 @ fr_w2 + fr_b2          (f32 + bf16 copies)
//     h2     = gelu(h1 @ M2 + c2),  M2 = fr_w2@tc_w1 (precomputed GEMM),
//                                   c2 = fr_b2@tc_w1 + tc_b1
//   w = softmax(h2 @ S^T + bc),  S = centers@tc_w2^T (folded tc2) [small]
//   joint2 over x_ring_bf16 (Nout=2048, K=1024):                 [68.7 GF]
//     gate = sigmoid(x_ring@g_w_top  + w@G2 + g_b)   G2 = centers@g_w_bot
//     fch  = gelu  (x_ring@fc_w1_top + w@F2 + fc_b1) F2 = centers@fc_w1_bot
//   out = gate*(fch @ fc_w2 + fc_b2) + (1-gate)*x_ring           [34 GF]
//
// R6: single-barrier-per-K-step pipeline (fix for R5's 4-barrier lockstep
// which serialized the ~1.15k-cyc LDS-read drain against the ~1.24k-cyc
// MFMA pipe; measured 2916 cyc/step = sum not max). Ring-4 LDS, staging
// depth 2, counted vmcnt(4) (never 0 in loop), counted lgkmcnt(4)/(0)
// splitting the 32-MFMA cluster so read service overlaps MFMA issue.
// Race proof: stage(s+2) writes slot (s-2)&3; every wave serviced its
// reads of that slot (lgkmcnt(0) at iter s-2) before reaching barrier(s-1),
// and stage(s+2) follows barrier(s-1) in program order.

__device__ __forceinline__ float bf2f(u16 b) {
  return __uint_as_float(((unsigned int)b) << 16);
}
__device__ __forceinline__ u16 f2bf(float f) {
  unsigned int u = __float_as_uint(f);
  u += 0x7FFFu + ((u >> 16) & 1u);   // round-to-nearest-even (finite inputs)
  return (u16)(u >> 16);
}
__device__ __forceinline__ float gelu_exact(float x) {
  return 0.5f * x * (1.0f + erff(x * 0.70710678118654752f));
}

// async 16B/lane global->LDS. LDS dest is wave-uniform base + lane*16.
__device__ __forceinline__ void cp16(const void* g, void* l) {
  __builtin_amdgcn_global_load_lds(
      (const __attribute__((address_space(1))) unsigned int*)g,
      (__attribute__((address_space(3))) unsigned int*)l, 16, 0, 0);
}

// ---------------------------------------------------------------------------
// gemm256: C[M,Nout] = A[M,K](bf16) @ Wt[Nout,K]^T(bf16)
// 256x256 tile, BK=32, ring-4 LDS, 512 threads (8 waves 2x4),
// per-wave 128x64 out = acc[8][4] of 16x16x32 MFMA.
//
// LDS layout per buffer (A 16KB then B 16KB): paired-row swizzle.
//   Superrow sr = row>>1 (128B). Slot qq in [0,8) of 16B. Content of
//   (sr,qq): row = sr*2 + (qqp>>2), kquad = qqp&3, qqp = qq ^ (sr&7).
//   Writes are linear (wave-uniform base + lane*16, m173: source is
//   pre-inverse-swizzled); reads use qq = ((row&1)*4 + kq) ^ (sr&7).
//   Bank check: 64-lane b128 read puts exactly 2 lanes on each 16B slot
//   group => even 8 words/bank (conflict-free aggregate).
//
// vmcnt ledger (4 loads/step/thread, staged 2 steps ahead):
//   prologue stages steps 0,1 (8 loads, no wait).
//   iter s: stage(s+2) [outstanding {s+1:4, s+2:4}], vmcnt(4) confirms
//   s+1; slot s was confirmed at iter s-1; barrier publishes. Tail clamps
//   the *source* step (dest ring slot never read again) so the counted
//   wait stays valid.
// ---------------------------------------------------------------------------
template <int MODE, bool GATHER>
__global__ __launch_bounds__(512) void gemm256(
    const u16* __restrict__ A, int lda, const u16* __restrict__ Wt, int K,
    const float* __restrict__ bias, const float* __restrict__ bias2,
    void* __restrict__ out0, int ldo0, void* __restrict__ out1,
    void* __restrict__ out2, const float* __restrict__ p0,
    const float* __restrict__ p1, const float* __restrict__ p2) {
  extern __shared__ __align__(16) char sm[];   // 4 bufs * 32 KB = 128 KB
  const int tid = threadIdx.x;
  const int lane = tid & 63;
  const int wave = tid >> 6;     // 0..7
  const int wm = wave >> 2;      // wave row in 2x4
  const int wn = wave & 3;       // wave col

  // ---- XCD-aware block swizzle (gridDim.y divisible by 8) ----
  const unsigned linear = blockIdx.y * gridDim.x + blockIdx.x;
  const unsigned xcd = linear & 7u;
  const unsigned pos = linear >> 3;
  const unsigned bx = pos % gridDim.x;
  const unsigned by = xcd * (gridDim.y >> 3) + pos / gridDim.x;
  const int m0 = by * 256;
  const int n0 = bx * 256;

  // staging (write-side) lane constants: lane covers (sr = chunk*8 + sl, qq)
  const int sl = lane >> 3;           // 0..7 superrow within 1KB chunk
  const int qqs = (lane & 7) ^ sl;    // pre-inverse-swizzled content slot
  const int rowoff = sl * 2 + (qqs >> 2);  // row within 16-row chunk
  const int colq = qqs & 3;                // k-quad (8 bf16) within BK=32

  // ds_read (read-side) lane constants
  const int r16 = lane & 15, q4 = lane >> 4;
  const int qqr = (((r16 & 1) << 2) | q4) ^ (r16 >> 1);
  const int laneA = wm * 8192 + (r16 >> 1) * 128 + qqr * 16;  // bytes
  const int laneB = wn * 4096 + (r16 >> 1) * 128 + qqr * 16;

  const int nt = K >> 5;   // K/32 steps

  f32x4 acc[8][4];
#pragma unroll
  for (int i = 0; i < 8; i++)
#pragma unroll
    for (int j = 0; j < 4; j++) acc[i][j] = (f32x4){0.f, 0.f, 0.f, 0.f};

  auto stage_A = [&](int sdst, int ssrc) {
#pragma unroll
    for (int i = 0; i < 2; i++) {
      const int chunk = wave + i * 8;        // 0..15 (1KB each)
      const int row = chunk * 16 + rowoff;   // 0..255 tile row
      long gofs;
      if (GATHER) {
        const int kg = ssrc * 32 + colq * 8;  // global k (seg-uniform per step)
        const int seg = kg >> 10;
        int shift;
        switch (seg) {
          case 0: shift = 1; break;
          case 1: shift = -1; break;
          case 2: shift = 0; break;
          case 3: shift = 2; break;
          case 4: shift = -2; break;
          case 5: shift = 4; break;
          default: shift = -4; break;
        }
        const int m = m0 + row;
        const int b = m >> 11;                 // N = 2048 = 2^11
        const int nsrc = ((m & 2047) - shift) & 2047;
        gofs = (long)((b << 11) | nsrc) * 1024 + (kg & 1023);
      } else {
        gofs = (long)(m0 + row) * lda + ssrc * 32 + colq * 8;
      }
      cp16(A + gofs, sm + (sdst & 3) * 32768 + chunk * 1024);
    }
  };
  auto stage_B = [&](int sdst, int ssrc) {
#pragma unroll
    for (int i = 0; i < 2; i++) {
      const int chunk = wave + i * 8;
      const int row = chunk * 16 + rowoff;
      const long gofs = (long)(n0 + row) * K + ssrc * 32 + colq * 8;
      cp16(Wt + gofs, sm + (sdst & 3) * 32768 + 16384 + chunk * 1024);
    }
  };

  // ---- prologue: stage steps 0,1 (no wait; iter 0's vmcnt(4) covers) ----
  stage_A(0, 0); stage_B(0, 0);
  stage_A(1, 1); stage_B(1, 1);

  for (int s = 0; s < nt; ++s) {
    const int s2 = (s + 2 < nt) ? s + 2 : nt - 1;  // clamped source step
    stage_A(s + 2, s2);
    stage_B(s + 2, s2);
    asm volatile("s_waitcnt vmcnt(4)" ::: "memory");  // step s+1 landed
    __builtin_amdgcn_s_barrier();                     // slot s published

    const char* abase = sm + (s & 3) * 32768;
    short8 af[8], bf[4];
#pragma unroll
    for (int ni = 0; ni < 4; ni++)
      bf[ni] = *(const short8*)(abase + 16384 + laneB + ni * 1024);
#pragma unroll
    for (int mi = 0; mi < 8; mi++)
      af[mi] = *(const short8*)(abase + laneA + mi * 1024);

    asm volatile("s_waitcnt lgkmcnt(4)" ::: "memory");  // bf[], af[0..3] ready
    __builtin_amdgcn_sched_barrier(0);
    __builtin_amdgcn_s_setprio(1);
#pragma unroll
    for (int mi = 0; mi < 4; mi++)
#pragma unroll
      for (int ni = 0; ni < 4; ni++)
        acc[mi][ni] = __builtin_amdgcn_mfma_f32_16x16x32_bf16(
            af[mi], bf[ni], acc[mi][ni], 0, 0, 0);
    __builtin_amdgcn_s_setprio(0);

    asm volatile("s_waitcnt lgkmcnt(0)" ::: "memory");  // af[4..7] ready
    __builtin_amdgcn_sched_barrier(0);
    __builtin_amdgcn_s_setprio(1);
#pragma unroll
    for (int mi = 0; mi < 4; mi++)
#pragma unroll
      for (int ni = 0; ni < 4; ni++)
        acc[4 + mi][ni] = __builtin_amdgcn_mfma_f32_16x16x32_bf16(
            af[4 + mi], bf[ni], acc[4 + mi][ni], 0, 0, 0);
    __builtin_amdgcn_s_setprio(0);
  }
  asm volatile("s_waitcnt vmcnt(0)" ::: "memory");  // drain tail re-stages

  // epilogue: C/D layout col = lane&15, row = (lane>>4)*4 + reg
  const int ccol = lane & 15;
  const int crow = (lane >> 4) * 4;
#pragma unroll
  for (int mi = 0; mi < 8; mi++) {
#pragma unroll
    for (int r = 0; r < 4; r++) {
      const int m = m0 + wm * 128 + mi * 16 + crow + r;
      float4 wrow;
      if (MODE == 8) wrow = *(const float4*)(p0 + (size_t)m * 4);
#pragma unroll
      for (int ni = 0; ni < 4; ni++) {
        const int n = n0 + wn * 64 + ni * 16 + ccol;
        const float v = acc[mi][ni][r];
        if (MODE == 0) {
          ((u16*)out0)[(long)m * ldo0 + n] = f2bf(gelu_exact(v + bias[n]));
        } else if (MODE == 4) {
          const float g = p0[(long)m * 1024 + n];
          const float xr = p1[(long)m * 1024 + n];
          ((float*)out0)[(long)m * ldo0 + n] =
              g * (v + bias[n]) + (1.0f - g) * xr;
        } else if (MODE == 6) {
          ((u16*)out0)[(long)m * ldo0 + n] = f2bf(v);
        } else if (MODE == 7) {
          if (n < 1024) {
            const float s = v + bias[n];
            ((float*)out1)[(long)m * 1024 + n] = s;
            ((u16*)out0)[(long)m * 1024 + n] = f2bf(s);
          } else {
            const int nn = n - 1024;
            ((u16*)out2)[(long)m * 1024 + nn] = f2bf(gelu_exact(v + bias2[nn]));
          }
        } else if (MODE == 8) {
          if (n < 1024) {
            const float4 g2 = *(const float4*)(p1 + (size_t)n * 4);
            const float s = v + bias[n] + wrow.x * g2.x + wrow.y * g2.y +
                            wrow.z * g2.z + wrow.w * g2.w;
            ((float*)out0)[(long)m * 1024 + n] = 1.0f / (1.0f + expf(-s));
          } else {
            const int nn = n - 1024;
            const float4 f2 = *(const float4*)(p2 + (size_t)nn * 4);
            const float s = v + bias2[nn] + wrow.x * f2.x + wrow.y * f2.y +
                            wrow.z * f2.z + wrow.w * f2.w;
            ((u16*)out1)[(long)m * 1024 + nn] = f2bf(gelu_exact(s));
          }
        }
      }
    }
  }
}

// ---------------------------------------------------------------------------
// gemm128 (m97-class, kept only for the small M2 precompute: M=1024, MODE 6)
// ---------------------------------------------------------------------------
template <int MODE, bool GATHER>
__global__ __launch_bounds__(256) void gemm128(
    const u16* __restrict__ A, int lda, const u16* __restrict__ Wt, int K,
    const float* __restrict__ bias, const float* __restrict__ bias2,
    void* __restrict__ out0, int ldo0, void* __restrict__ out1,
    void* __restrict__ out2, const float* __restrict__ p0,
    const float* __restrict__ p1, const float* __restrict__ p2) {
  __shared__ __align__(16) u16 As[128 * 64];
  __shared__ __align__(16) u16 Bs[128 * 64];

  const int tid = threadIdx.x;
  const int lane = tid & 63;
  const int wave = tid >> 6;     // 0..3
  const int wm = wave >> 1;      // wave row in 2x2
  const int wn = wave & 1;       // wave col

  const unsigned linear = blockIdx.y * gridDim.x + blockIdx.x;
  const unsigned xcd = linear & 7u;
  const unsigned pos = linear >> 3;
  const unsigned bx = pos % gridDim.x;
  const unsigned by = xcd * (gridDim.y >> 3) + pos / gridDim.x;
  const int m0 = by * 128;
  const int n0 = bx * 128;

  const int srow = lane >> 3;    // 0..7: row within an 8-row staging chunk
  const int sq = lane & 7;       // quad (16B) within a 128B row
  const int sqs = sq ^ srow;     // swizzled global quad

  f32x4 acc[4][4];
#pragma unroll
  for (int i = 0; i < 4; i++)
#pragma unroll
    for (int j = 0; j < 4; j++) acc[i][j] = (f32x4){0.f, 0.f, 0.f, 0.f};

  for (int k0 = 0; k0 < K; k0 += 64) {
#pragma unroll
    for (int i = 0; i < 4; i++) {
      const int rloc = wave * 32 + i * 8 + srow;   // 0..127
      long gofs;
      if (GATHER) {
        const int seg = k0 >> 10;
        int shift;
        switch (seg) {
          case 0: shift = 1; break;
          case 1: shift = -1; break;
          case 2: shift = 0; break;
          case 3: shift = 2; break;
          case 4: shift = -2; break;
          case 5: shift = 4; break;
          default: shift = -4; break;
        }
        const int m = m0 + rloc;
        const int b = m >> 11;
        const int nsrc = ((m & 2047) - shift) & 2047;
        gofs = (long)((b << 11) | nsrc) * 1024 + (k0 & 1023) + sqs * 8;
      } else {
        gofs = (long)(m0 + rloc) * lda + k0 + sqs * 8;
      }
      cp16(A + gofs, &As[(wave * 32 + i * 8) * 64]);
    }
#pragma unroll
    for (int i = 0; i < 4; i++) {
      const int rloc = wave * 32 + i * 8 + srow;
      const long gofs = (long)(n0 + rloc) * K + k0 + sqs * 8;
      cp16(Wt + gofs, &Bs[(wave * 32 + i * 8) * 64]);
    }
    __syncthreads();

    const int q4 = lane >> 4;     // 0..3
    const int r16 = lane & 15;
#pragma unroll
    for (int kk = 0; kk < 2; kk++) {
      short8 af[4], bf[4];
#pragma unroll
      for (int mi = 0; mi < 4; mi++) {
        const int row = wm * 64 + mi * 16 + r16;
        const int q = (kk * 4 + q4) ^ (row & 7);
        af[mi] = *(const short8*)&As[row * 64 + q * 8];
      }
#pragma unroll
      for (int ni = 0; ni < 4; ni++) {
        const int row = wn * 64 + ni * 16 + r16;
        const int q = (kk * 4 + q4) ^ (row & 7);
        bf[ni] = *(const short8*)&Bs[row * 64 + q * 8];
      }
#pragma unroll
      for (int mi = 0; mi < 4; mi++)
#pragma unroll
        for (int ni = 0; ni < 4; ni++)
          acc[mi][ni] = __builtin_amdgcn_mfma_f32_16x16x32_bf16(
              af[mi], bf[ni], acc[mi][ni], 0, 0, 0);
    }
    __syncthreads();
  }

  const int ccol = lane & 15;
  const int crow = (lane >> 4) * 4;
#pragma unroll
  for (int mi = 0; mi < 4; mi++) {
#pragma unroll
    for (int r = 0; r < 4; r++) {
      const int m = m0 + wm * 64 + mi * 16 + crow + r;
#pragma unroll
      for (int ni = 0; ni < 4; ni++) {
        const int n = n0 + wn * 64 + ni * 16 + ccol;
        const float v = acc[mi][ni][r];
        if (MODE == 6) {
          ((u16*)out0)[(long)m * ldo0 + n] = f2bf(v);
        }
      }
    }
  }
}

// fp32 -> bf16 cast, 4 elems/thread
__global__ __launch_bounds__(256) void cast_bf16(const float* __restrict__ in,
                                                 u16* __restrict__ out, int n4) {
  const long i = (long)blockIdx.x * 256 + threadIdx.x;
  if (i < n4) {
    const float4 v = ((const float4*)in)[i];
    ushort4 o;
    o.x = f2bf(v.x); o.y = f2bf(v.y); o.z = f2bf(v.z); o.w = f2bf(v.w);
    ((ushort4*)out)[i] = o;
  }
}

// W[K,N] fp32 -> Wt[N,K] bf16, 32x32 LDS tile transpose. K = OUT row length.
__global__ __launch_bounds__(256) void transp_bf16(const float* __restrict__ in,
                                                   u16* __restrict__ out, int K,
                                                   int N) {
  __shared__ float tile[32][33];
  const int tx = threadIdx.x & 31;
  const int ty = threadIdx.x >> 5;  // 0..7
  const long r0 = (long)blockIdx.y * 32;
  const long c0 = (long)blockIdx.x * 32;
#pragma unroll
  for (int r = 0; r < 4; r++)
    tile[ty + r * 8][tx] = in[(r0 + ty + r * 8) * N + c0 + tx];
  __syncthreads();
#pragma unroll
  for (int r = 0; r < 4; r++)
    out[(c0 + ty + r * 8) * K + r0 + tx] = f2bf(tile[tx][ty + r * 8]);
}

// All small precomputed folds in one launch (769 blocks, 4 waves each)
__global__ __launch_bounds__(256) void fold_all(
    const u16* __restrict__ GbT, const u16* __restrict__ FbT,
    const u16* __restrict__ Wt3, const float* __restrict__ centers,
    const float* __restrict__ fr_b2, const float* __restrict__ tc_b1,
    const float* __restrict__ tc_w2, const float* __restrict__ tc_b2,
    float* __restrict__ G2T, float* __restrict__ F2T, float* __restrict__ c2,
    float* __restrict__ S, float* __restrict__ bc) {
  const int b = blockIdx.x;
  const int wave = threadIdx.x >> 6, lane = threadIdx.x & 63;
  if (b < 256) {
    const int n = b * 4 + wave;
    float g[4] = {0.f, 0.f, 0.f, 0.f}, f[4] = {0.f, 0.f, 0.f, 0.f};
#pragma unroll
    for (int p = 0; p < 2; p++) {
      const int base = p * 512 + lane * 8;
      const short8 gv = *(const short8*)(GbT + (long)n * 1024 + base);
      const short8 fv = *(const short8*)(FbT + (long)n * 1024 + base);
#pragma unroll
      for (int e = 0; e < 8; e++) {
        const float ge = bf2f((u16)gv[e]), fe = bf2f((u16)fv[e]);
#pragma unroll
        for (int k = 0; k < 4; k++) {
          const float c = centers[k * 1024 + base + e];
          g[k] += ge * c;
          f[k] += fe * c;
        }
      }
    }
#pragma unroll
    for (int k = 0; k < 4; k++)
#pragma unroll
      for (int off = 32; off > 0; off >>= 1) {
        g[k] += __shfl_xor(g[k], off);
        f[k] += __shfl_xor(f[k], off);
      }
    if (lane == 0) {
#pragma unroll
      for (int k = 0; k < 4; k++) {
        G2T[n * 4 + k] = g[k];
        F2T[n * 4 + k] = f[k];
      }
    }
  } else if (b < 512) {
    const int j = (b - 256) * 4 + wave;
    float s = 0.f;
#pragma unroll
    for (int p = 0; p < 2; p++) {
      const int base = p * 512 + lane * 8;
      const short8 wv = *(const short8*)(Wt3 + (long)j * 1024 + base);
#pragma unroll
      for (int e = 0; e < 8; e++) s += fr_b2[base + e] * bf2f((u16)wv[e]);
    }
#pragma unroll
    for (int off = 32; off > 0; off >>= 1) s += __shfl_xor(s, off);
    if (lane == 0) c2[j] = s + tc_b1[j];
  } else if (b < 768) {
    const int d = (b - 512) * 4 + wave;
    const float* row = tc_w2 + (long)d * 1024;
    float s0 = 0.f, s1 = 0.f, s2 = 0.f, s3 = 0.f;
    for (int e = lane; e < 1024; e += 64) {
      const float w = row[e];
      s0 += w * centers[e];
      s1 += w * centers[1024 + e];
      s2 += w * centers[2048 + e];
      s3 += w * centers[3072 + e];
    }
#pragma unroll
    for (int off = 32; off > 0; off >>= 1) {
      s0 += __shfl_xor(s0, off);
      s1 += __shfl_xor(s1, off);
      s2 += __shfl_xor(s2, off);
      s3 += __shfl_xor(s3, off);
    }
    if (lane == 0) {
      S[d] = s0; S[1024 + d] = s1; S[2048 + d] = s2; S[3072 + d] = s3;
    }
  } else {
    const int k = wave;
    float s = 0.f;
    for (int e = lane; e < 1024; e += 64) s += tc_b2[e] * centers[k * 1024 + e];
#pragma unroll
    for (int off = 32; off > 0; off >>= 1) s += __shfl_xor(s, off);
    if (lane == 0) bc[k] = s;
  }
}

// w = softmax(h2 @ S^T + bc) over 4 centers; one wave per token -> w[t][0..3]
__global__ __launch_bounds__(256) void centers_kernel(
    const u16* __restrict__ h2, const float* __restrict__ S,
    const float* __restrict__ bc, float* __restrict__ wtok) {
  const int lane = threadIdx.x & 63;
  const int wave = threadIdx.x >> 6;
  const long t = (long)blockIdx.x * 4 + wave;
  const u16* row = h2 + t * 1024;
  float d0 = 0.f, d1 = 0.f, d2 = 0.f, d3 = 0.f;
#pragma unroll
  for (int j = 0; j < 2; j++) {
    const int dbase = j * 512 + lane * 8;
    const short8 v = *(const short8*)(row + dbase);
#pragma unroll
    for (int e = 0; e < 8; e++) {
      const float x = bf2f((u16)v[e]);
      const int d = dbase + e;
      d0 += x * S[d];
      d1 += x * S[1024 + d];
      d2 += x * S[2048 + d];
      d3 += x * S[3072 + d];
    }
  }
#pragma unroll
  for (int off = 32; off > 0; off >>= 1) {
    d0 += __shfl_xor(d0, off);
    d1 += __shfl_xor(d1, off);
    d2 += __shfl_xor(d2, off);
    d3 += __shfl_xor(d3, off);
  }
  if (lane == 0) {
    d0 += bc[0]; d1 += bc[1]; d2 += bc[2]; d3 += bc[3];
    const float mx = fmaxf(fmaxf(d0, d1), fmaxf(d2, d3));
    float e0 = expf(d0 - mx), e1 = expf(d1 - mx), e2 = expf(d2 - mx),
          e3 = expf(d3 - mx);
    const float inv = 1.0f / (e0 + e1 + e2 + e3);
    *(float4*)(wtok + t * 4) = (float4){e0 * inv, e1 * inv, e2 * inv, e3 * inv};
  }
}

extern "C" void kernel_launch(void* const* d_in, const int* in_sizes, int n_in,
                              void* d_out, int out_size, void* d_ws,
                              size_t ws_size, hipStream_t stream) {
  const float* queries = (const float*)d_in[0];
  const float* fr_w1 = (const float*)d_in[1];
  const float* fr_b1 = (const float*)d_in[2];
  const float* fr_w2 = (const float*)d_in[3];
  const float* fr_b2 = (const float*)d_in[4];
  const float* tc_w1 = (const float*)d_in[5];
  const float* tc_b1 = (const float*)d_in[6];
  const float* tc_w2 = (const float*)d_in[7];
  const float* tc_b2 = (const float*)d_in[8];
  const float* centers = (const float*)d_in[9];
  const float* fc_w1 = (const float*)d_in[10];
  const float* fc_b1 = (const float*)d_in[11];
  const float* fc_w2 = (const float*)d_in[12];
  const float* fc_b2 = (const float*)d_in[13];
  const float* g_w = (const float*)d_in[14];
  const float* g_b = (const float*)d_in[15];

  char* ws = (char*)d_ws;
  u16* Wt1 = (u16*)ws; ws += (size_t)7168 * 1024 * 2;   // fr_w1^T
  u16* Wt3 = (u16*)ws; ws += (size_t)1024 * 1024 * 2;   // tc_w1^T
  u16* Wt6 = (u16*)ws; ws += (size_t)1024 * 1024 * 2;   // fc_w2^T
  u16* WtJ = (u16*)ws; ws += (size_t)2048 * 1024 * 2;   // [fr_w2^T ; M2^T]
  u16* WtG2 = (u16*)ws; ws += (size_t)2048 * 1024 * 2;  // [g_w_top^T ; fc_w1_top^T]
  u16* Fw2b = (u16*)ws; ws += (size_t)1024 * 1024 * 2;  // fr_w2 bf16 (row-major)
  u16* GbT = (u16*)ws; ws += (size_t)1024 * 1024 * 2;   // g_w_bot^T bf16
  u16* FbT = (u16*)ws; ws += (size_t)1024 * 1024 * 2;   // fc_w1_bot^T bf16
  u16* Xb = (u16*)ws;  ws += (size_t)16384 * 1024 * 2;  // bf16 queries -> h2
  u16* h1 = (u16*)ws;  ws += (size_t)16384 * 1024 * 2;  // ring hidden -> fch
  u16* xrb = (u16*)ws; ws += (size_t)16384 * 1024 * 2;  // x_ring bf16
  float* xring = (float*)ws; ws += (size_t)16384 * 1024 * 4;  // x_ring f32
  float* wtok = (float*)ws; ws += (size_t)16384 * 4 * 4;      // softmax weights
  float* S = (float*)ws; ws += (size_t)4 * 1024 * 4;
  float* G2T = (float*)ws; ws += (size_t)1024 * 4 * 4;
  float* F2T = (float*)ws; ws += (size_t)1024 * 4 * 4;
  float* c2 = (float*)ws; ws += (size_t)1024 * 4;
  float* bc = (float*)ws; ws += 16;
  float* gate = (float*)d_out;  // gate f32 in d_out (read-then-overwrite)
  float* out = (float*)d_out;

  // allow 128 KB dynamic LDS on the big-tile GEMM (host-side, capture-safe)
  static bool attr_set = false;
  if (!attr_set) {
    attr_set = true;
    (void)hipFuncSetAttribute((const void*)gemm256<0, true>,
                              hipFuncAttributeMaxDynamicSharedMemorySize,
                              131072);
    (void)hipFuncSetAttribute((const void*)gemm256<7, false>,
                              hipFuncAttributeMaxDynamicSharedMemorySize,
                              131072);
    (void)hipFuncSetAttribute((const void*)gemm256<8, false>,
                              hipFuncAttributeMaxDynamicSharedMemorySize,
                              131072);
    (void)hipFuncSetAttribute((const void*)gemm256<4, false>,
                              hipFuncAttributeMaxDynamicSharedMemorySize,
                              131072);
  }

  // --- conversions / transposes ---
  cast_bf16<<<16384, 256, 0, stream>>>(queries, Xb, 16384 * 1024 / 4);
  cast_bf16<<<1024, 256, 0, stream>>>(fr_w2, Fw2b, 1024 * 1024 / 4);
  transp_bf16<<<dim3(32, 224), 256, 0, stream>>>(fr_w1, Wt1, 7168, 1024);
  transp_bf16<<<dim3(32, 32), 256, 0, stream>>>(tc_w1, Wt3, 1024, 1024);
  transp_bf16<<<dim3(32, 32), 256, 0, stream>>>(fc_w2, Wt6, 1024, 1024);
  transp_bf16<<<dim3(32, 32), 256, 0, stream>>>(fr_w2, WtJ, 1024, 1024);
  transp_bf16<<<dim3(32, 32), 256, 0, stream>>>(g_w, WtG2, 1024, 1024);
  transp_bf16<<<dim3(32, 32), 256, 0, stream>>>(fc_w1,
                                                WtG2 + (size_t)1024 * 1024,
                                                1024, 1024);
  transp_bf16<<<dim3(32, 32), 256, 0, stream>>>(g_w + (size_t)1024 * 1024, GbT,
                                                1024, 1024);
  transp_bf16<<<dim3(32, 32), 256, 0, stream>>>(fc_w1 + (size_t)1024 * 1024,
                                                FbT, 1024, 1024);
  // --- small folds: G2T/F2T, c2, S, bc ---
  fold_all<<<769, 256, 0, stream>>>(GbT, FbT, Wt3, centers, fr_b2, tc_b1,
                                    tc_w2, tc_b2, G2T, F2T, c2, S, bc);
  // --- M2^T = (fr_w2 @ tc_w1)^T via GEMM: C[j][i] = sum_e Wt3[j][e]*Fw2b[i][e]
  gemm128<6, false><<<dim3(8, 8), 256, 0, stream>>>(
      Wt3, 1024, Fw2b, 1024, nullptr, nullptr, WtJ + (size_t)1024 * 1024, 1024,
      nullptr, nullptr, nullptr, nullptr, nullptr);

  // --- main chain (256x256 single-barrier pipelined GEMMs) ---
  // fr1: h1 = gelu(ring_gather(x) @ fr_w1 + fr_b1)
  gemm256<0, true><<<dim3(4, 64), 512, 131072, stream>>>(
      Xb, 0, Wt1, 7168, fr_b1, nullptr, h1, 1024, nullptr, nullptr, nullptr,
      nullptr, nullptr);
  // joint1: x_ring (f32 + bf16) and h2 in one pass over h1
  gemm256<7, false><<<dim3(8, 64), 512, 131072, stream>>>(
      h1, 1024, WtJ, 1024, fr_b2, c2, xrb, 1024, xring, Xb, nullptr, nullptr,
      nullptr);
  // w = softmax(h2 @ S^T + bc)
  centers_kernel<<<4096, 256, 0, stream>>>(Xb, S, bc, wtok);
  // joint2: gate -> d_out, fch -> h1 (w-corrections in epilogue)
  gemm256<8, false><<<dim3(8, 64), 512, 131072, stream>>>(
      xrb, 1024, WtG2, 1024, g_b, fc_b1, gate, 1024, h1, nullptr, wtok, G2T,
      F2T);
  // fc2 + final mix: out = gate*(fch @ fc_w2 + fc_b2) + (1-gate)*x_ring
  gemm256<4, false><<<dim3(4, 64), 512, 131072, stream>>>(
      h1, 1024, Wt6, 1024, fc_b2, nullptr, out, 1024, nullptr, nullptr, gate,
      xring, nullptr);
}

// Round 3
// 795.723 us; speedup vs baseline: 1.0856x; 1.0187x over previous
//
#include <hip/hip_runtime.h>
#include <hip/hip_bf16.h>
#include <math.h>

typedef unsigned short u16;
typedef __attribute__((ext_vector_type(8))) short short8;   // 8 bf16 (4 VGPRs)
typedef __attribute__((ext_vector_type(4))) float f32x4;    // MFMA C/D frag

// Problem constants: B=8, N=2048, D=DC=1024, K_centers=4, M = B*N = 16384.
//
// R4 algebra (no fus2, no tc2, no tc1 as separate GEMMs):
//   h1    = gelu(ring_gather(x) @ fr_w1 + fr_b1)                 [240 GF]
//   joint1 over h1 (Nout=2048, K=1024):                          [68.7 GF]
//     x_ring = h1 @ fr_w2 + fr_b2          (f32 + bf16 copies)
//     h2     = gelu(h1 @ M2 + c2),  M2 = fr_w2@tc_w1 (precomputed GEMM),
//                                   c2 = fr_b2@tc_w1 + tc_b1
//   w = softmax(h2 @ S^T + bc),  S = centers@tc_w2^T (folded tc2) [small]
//   joint2 over x_ring_bf16 (Nout=2048, K=1024):                 [68.7 GF]
//     gate = sigmoid(x_ring@g_w_top  + w@G2 + g_b)   G2 = centers@g_w_bot
//     fch  = gelu  (x_ring@fc_w1_top + w@F2 + fc_b1) F2 = centers@fc_w1_bot
//   out = gate*(fch @ fc_w2 + fc_b2) + (1-gate)*x_ring           [34 GF]
//
// R7: cross-step fragment prefetch. R6 measured 2822 cyc/step = MFMA(1242)
// + LDS(~1440) SERIALIZED: the first MFMA group waited on reads issued the
// same step (a wave's first 8 reads retire after ~2/3 of the 96-read CU
// queue). Now step s prefetches step s+1's first-group frags (bf[0..3],
// af[0..1]) during its own MFMA cluster, so MFMAs start at barrier release
// and the 12 reads/wave service UNDER the 1242-cyc MFMA cluster, paced by
// a counted lgkmcnt ladder (12/10/8/6; DS retires FIFO).
// Staging depth 3 on ring-4: at iter s issue stage(s+3), vmcnt(4) confirms
// slot s+2 -> barrier(s) publishes s+1,s+2 -> prefetch of s+1 at iter s is
// after barrier(s-1) which published s+1. Write-slot (s+3)&3=(s-1)&3 was
// last read (remainder) at iter s-1 before its barrier. Loop unrolled x2
// for static reg double-buffer (nt even at all call sites).

__device__ __forceinline__ float bf2f(u16 b) {
  return __uint_as_float(((unsigned int)b) << 16);
}
__device__ __forceinline__ u16 f2bf(float f) {
  unsigned int u = __float_as_uint(f);
  u += 0x7FFFu + ((u >> 16) & 1u);   // round-to-nearest-even (finite inputs)
  return (u16)(u >> 16);
}
__device__ __forceinline__ float gelu_exact(float x) {
  return 0.5f * x * (1.0f + erff(x * 0.70710678118654752f));
}

// async 16B/lane global->LDS. LDS dest is wave-uniform base + lane*16.
__device__ __forceinline__ void cp16(const void* g, void* l) {
  __builtin_amdgcn_global_load_lds(
      (const __attribute__((address_space(1))) unsigned int*)g,
      (__attribute__((address_space(3))) unsigned int*)l, 16, 0, 0);
}

// ---------------------------------------------------------------------------
// gemm256: C[M,Nout] = A[M,K](bf16) @ Wt[Nout,K]^T(bf16)
// 256x256 tile, BK=32, ring-4 LDS, 512 threads (8 waves 2x4),
// per-wave 128x64 out = acc[8][4] of 16x16x32 MFMA.
//
// LDS layout per buffer (A 16KB then B 16KB): paired-row swizzle (as R5/R6).
// vmcnt ledger (4 cp16/step, staged 3 ahead): enter iter s with {s+2:4};
// issue stage(s+3) -> 8; vmcnt(4) (late, before barrier) confirms s+2.
// lgkm ledger (DS FIFO): enter with 6 (prev prefetch); +6 remainder
// (af[2..7] of slot s) -> 12; +6 prefetch (slot s+1: bf[0..3], af[0..1])
// -> 18; lgkm(12)=prev-pf done; lgkm(10)=af2,3; lgkm(8)=af4,5;
// lgkm(6)=af6,7; exit with 6. Compiler auto-waits guarantee correctness;
// the asm ladder pins pacing (sched_barrier(0) per rule #18).
// ---------------------------------------------------------------------------
template <int MODE, bool GATHER>
__global__ __launch_bounds__(512) void gemm256(
    const u16* __restrict__ A, int lda, const u16* __restrict__ Wt, int K,
    const float* __restrict__ bias, const float* __restrict__ bias2,
    void* __restrict__ out0, int ldo0, void* __restrict__ out1,
    void* __restrict__ out2, const float* __restrict__ p0,
    const float* __restrict__ p1, const float* __restrict__ p2) {
  extern __shared__ __align__(16) char sm[];   // 4 bufs * 32 KB = 128 KB
  const int tid = threadIdx.x;
  const int lane = tid & 63;
  const int wave = tid >> 6;     // 0..7
  const int wm = wave >> 2;      // wave row in 2x4
  const int wn = wave & 3;       // wave col

  // ---- XCD-aware block swizzle (gridDim.y divisible by 8) ----
  const unsigned linear = blockIdx.y * gridDim.x + blockIdx.x;
  const unsigned xcd = linear & 7u;
  const unsigned pos = linear >> 3;
  const unsigned bx = pos % gridDim.x;
  const unsigned by = xcd * (gridDim.y >> 3) + pos / gridDim.x;
  const int m0 = by * 256;
  const int n0 = bx * 256;

  // staging (write-side) lane constants: lane covers (sr = chunk*8 + sl, qq)
  const int sl = lane >> 3;           // 0..7 superrow within 1KB chunk
  const int qqs = (lane & 7) ^ sl;    // pre-inverse-swizzled content slot
  const int rowoff = sl * 2 + (qqs >> 2);  // row within 16-row chunk
  const int colq = qqs & 3;                // k-quad (8 bf16) within BK=32

  // ds_read (read-side) lane constants
  const int r16 = lane & 15, q4 = lane >> 4;
  const int qqr = (((r16 & 1) << 2) | q4) ^ (r16 >> 1);
  const int laneA = wm * 8192 + (r16 >> 1) * 128 + qqr * 16;  // bytes
  const int laneB = wn * 4096 + (r16 >> 1) * 128 + qqr * 16;

  const int nt = K >> 5;   // K/32 steps (even for all call sites)

  f32x4 acc[8][4];
#pragma unroll
  for (int i = 0; i < 8; i++)
#pragma unroll
    for (int j = 0; j < 4; j++) acc[i][j] = (f32x4){0.f, 0.f, 0.f, 0.f};

  auto stage_A = [&](int sdst, int ssrc) {
#pragma unroll
    for (int i = 0; i < 2; i++) {
      const int chunk = wave + i * 8;        // 0..15 (1KB each)
      const int row = chunk * 16 + rowoff;   // 0..255 tile row
      long gofs;
      if (GATHER) {
        const int kg = ssrc * 32 + colq * 8;  // global k (seg-uniform per step)
        const int seg = kg >> 10;
        int shift;
        switch (seg) {
          case 0: shift = 1; break;
          case 1: shift = -1; break;
          case 2: shift = 0; break;
          case 3: shift = 2; break;
          case 4: shift = -2; break;
          case 5: shift = 4; break;
          default: shift = -4; break;
        }
        const int m = m0 + row;
        const int b = m >> 11;                 // N = 2048 = 2^11
        const int nsrc = ((m & 2047) - shift) & 2047;
        gofs = (long)((b << 11) | nsrc) * 1024 + (kg & 1023);
      } else {
        gofs = (long)(m0 + row) * lda + ssrc * 32 + colq * 8;
      }
      cp16(A + gofs, sm + (sdst & 3) * 32768 + chunk * 1024);
    }
  };
  auto stage_B = [&](int sdst, int ssrc) {
#pragma unroll
    for (int i = 0; i < 2; i++) {
      const int chunk = wave + i * 8;
      const int row = chunk * 16 + rowoff;
      const long gofs = (long)(n0 + row) * K + ssrc * 32 + colq * 8;
      cp16(Wt + gofs, sm + (sdst & 3) * 32768 + 16384 + chunk * 1024);
    }
  };

  // prefetch first-group frags of step s into (pbf, paf01)
  auto prefetch = [&](int s, short8 (&pbf)[4], short8 (&paf01)[2]) {
    const char* base = sm + (s & 3) * 32768;
#pragma unroll
    for (int ni = 0; ni < 4; ni++)
      pbf[ni] = *(const short8*)(base + 16384 + laneB + ni * 1024);
#pragma unroll
    for (int mi = 0; mi < 2; mi++)
      paf01[mi] = *(const short8*)(base + laneA + mi * 1024);
  };

  auto body = [&](int s, short8 (&cbf)[4], short8 (&caf01)[2],
                  short8 (&nbf)[4], short8 (&naf01)[2]) {
    const int s3c = (s + 3 < nt) ? s + 3 : nt - 1;  // clamped source step
    stage_A(s + 3, s3c);
    stage_B(s + 3, s3c);
    const char* abase = sm + (s & 3) * 32768;
    short8 afr[6];
#pragma unroll
    for (int j = 0; j < 6; j++)   // remainder A-frags: mi = j+2
      afr[j] = *(const short8*)(abase + laneA + (j + 2) * 1024);
    prefetch(s + 1, nbf, naf01);

    asm volatile("s_waitcnt lgkmcnt(12)" ::: "memory");  // prev prefetch done
    __builtin_amdgcn_sched_barrier(0);
    __builtin_amdgcn_s_setprio(1);
#pragma unroll
    for (int mi = 0; mi < 2; mi++)
#pragma unroll
      for (int ni = 0; ni < 4; ni++)
        acc[mi][ni] = __builtin_amdgcn_mfma_f32_16x16x32_bf16(
            caf01[mi], cbf[ni], acc[mi][ni], 0, 0, 0);

    asm volatile("s_waitcnt lgkmcnt(10)" ::: "memory");  // afr[0],afr[1]
    __builtin_amdgcn_sched_barrier(0);
#pragma unroll
    for (int j = 0; j < 2; j++)
#pragma unroll
      for (int ni = 0; ni < 4; ni++)
        acc[2 + j][ni] = __builtin_amdgcn_mfma_f32_16x16x32_bf16(
            afr[j], cbf[ni], acc[2 + j][ni], 0, 0, 0);

    asm volatile("s_waitcnt lgkmcnt(8)" ::: "memory");   // afr[2],afr[3]
    __builtin_amdgcn_sched_barrier(0);
#pragma unroll
    for (int j = 0; j < 2; j++)
#pragma unroll
      for (int ni = 0; ni < 4; ni++)
        acc[4 + j][ni] = __builtin_amdgcn_mfma_f32_16x16x32_bf16(
            afr[2 + j], cbf[ni], acc[4 + j][ni], 0, 0, 0);

    asm volatile("s_waitcnt lgkmcnt(6)" ::: "memory");   // afr[4],afr[5]
    __builtin_amdgcn_sched_barrier(0);
#pragma unroll
    for (int j = 0; j < 2; j++)
#pragma unroll
      for (int ni = 0; ni < 4; ni++)
        acc[6 + j][ni] = __builtin_amdgcn_mfma_f32_16x16x32_bf16(
            afr[4 + j], cbf[ni], acc[6 + j][ni], 0, 0, 0);
    __builtin_amdgcn_s_setprio(0);

    asm volatile("s_waitcnt vmcnt(4)" ::: "memory");  // slot s+2 landed (mine)
    __builtin_amdgcn_s_barrier();                     // publish s+1, s+2
  };

  // ---- prologue: stage 0,1,2; confirm 0,1; prefetch slot 0 ----
  stage_A(0, 0); stage_B(0, 0);
  stage_A(1, 1); stage_B(1, 1);
  stage_A(2, 2); stage_B(2, 2);
  asm volatile("s_waitcnt vmcnt(4)" ::: "memory");  // slots 0,1 landed
  __builtin_amdgcn_s_barrier();                     // published

  short8 bfA[4], afA[2], bfB[4], afB[2];
  prefetch(0, bfA, afA);   // 6 DS outstanding entering the loop

  for (int s = 0; s < nt; s += 2) {
    body(s, bfA, afA, bfB, afB);
    body(s + 1, bfB, afB, bfA, afA);
  }
  asm volatile("s_waitcnt vmcnt(0) lgkmcnt(0)" ::: "memory");  // drain tail

  // epilogue: C/D layout col = lane&15, row = (lane>>4)*4 + reg
  const int ccol = lane & 15;
  const int crow = (lane >> 4) * 4;
#pragma unroll
  for (int mi = 0; mi < 8; mi++) {
#pragma unroll
    for (int r = 0; r < 4; r++) {
      const int m = m0 + wm * 128 + mi * 16 + crow + r;
      float4 wrow;
      if (MODE == 8) wrow = *(const float4*)(p0 + (size_t)m * 4);
#pragma unroll
      for (int ni = 0; ni < 4; ni++) {
        const int n = n0 + wn * 64 + ni * 16 + ccol;
        const float v = acc[mi][ni][r];
        if (MODE == 0) {
          ((u16*)out0)[(long)m * ldo0 + n] = f2bf(gelu_exact(v + bias[n]));
        } else if (MODE == 4) {
          const float g = p0[(long)m * 1024 + n];
          const float xr = p1[(long)m * 1024 + n];
          ((float*)out0)[(long)m * ldo0 + n] =
              g * (v + bias[n]) + (1.0f - g) * xr;
        } else if (MODE == 6) {
          ((u16*)out0)[(long)m * ldo0 + n] = f2bf(v);
        } else if (MODE == 7) {
          if (n < 1024) {
            const float s = v + bias[n];
            ((float*)out1)[(long)m * 1024 + n] = s;
            ((u16*)out0)[(long)m * 1024 + n] = f2bf(s);
          } else {
            const int nn = n - 1024;
            ((u16*)out2)[(long)m * 1024 + nn] = f2bf(gelu_exact(v + bias2[nn]));
          }
        } else if (MODE == 8) {
          if (n < 1024) {
            const float4 g2 = *(const float4*)(p1 + (size_t)n * 4);
            const float s = v + bias[n] + wrow.x * g2.x + wrow.y * g2.y +
                            wrow.z * g2.z + wrow.w * g2.w;
            ((float*)out0)[(long)m * 1024 + n] = 1.0f / (1.0f + expf(-s));
          } else {
            const int nn = n - 1024;
            const float4 f2 = *(const float4*)(p2 + (size_t)nn * 4);
            const float s = v + bias2[nn] + wrow.x * f2.x + wrow.y * f2.y +
                            wrow.z * f2.z + wrow.w * f2.w;
            ((u16*)out1)[(long)m * 1024 + nn] = f2bf(gelu_exact(s));
          }
        }
      }
    }
  }
}

// ---------------------------------------------------------------------------
// gemm128 (m97-class, kept only for the small M2 precompute: M=1024, MODE 6)
// ---------------------------------------------------------------------------
template <int MODE, bool GATHER>
__global__ __launch_bounds__(256) void gemm128(
    const u16* __restrict__ A, int lda, const u16* __restrict__ Wt, int K,
    const float* __restrict__ bias, const float* __restrict__ bias2,
    void* __restrict__ out0, int ldo0, void* __restrict__ out1,
    void* __restrict__ out2, const float* __restrict__ p0,
    const float* __restrict__ p1, const float* __restrict__ p2) {
  __shared__ __align__(16) u16 As[128 * 64];
  __shared__ __align__(16) u16 Bs[128 * 64];

  const int tid = threadIdx.x;
  const int lane = tid & 63;
  const int wave = tid >> 6;     // 0..3
  const int wm = wave >> 1;      // wave row in 2x2
  const int wn = wave & 1;       // wave col

  const unsigned linear = blockIdx.y * gridDim.x + blockIdx.x;
  const unsigned xcd = linear & 7u;
  const unsigned pos = linear >> 3;
  const unsigned bx = pos % gridDim.x;
  const unsigned by = xcd * (gridDim.y >> 3) + pos / gridDim.x;
  const int m0 = by * 128;
  const int n0 = bx * 128;

  const int srow = lane >> 3;    // 0..7: row within an 8-row staging chunk
  const int sq = lane & 7;       // quad (16B) within a 128B row
  const int sqs = sq ^ srow;     // swizzled global quad

  f32x4 acc[4][4];
#pragma unroll
  for (int i = 0; i < 4; i++)
#pragma unroll
    for (int j = 0; j < 4; j++) acc[i][j] = (f32x4){0.f, 0.f, 0.f, 0.f};

  for (int k0 = 0; k0 < K; k0 += 64) {
#pragma unroll
    for (int i = 0; i < 4; i++) {
      const int rloc = wave * 32 + i * 8 + srow;   // 0..127
      long gofs;
      if (GATHER) {
        const int seg = k0 >> 10;
        int shift;
        switch (seg) {
          case 0: shift = 1; break;
          case 1: shift = -1; break;
          case 2: shift = 0; break;
          case 3: shift = 2; break;
          case 4: shift = -2; break;
          case 5: shift = 4; break;
          default: shift = -4; break;
        }
        const int m = m0 + rloc;
        const int b = m >> 11;
        const int nsrc = ((m & 2047) - shift) & 2047;
        gofs = (long)((b << 11) | nsrc) * 1024 + (k0 & 1023) + sqs * 8;
      } else {
        gofs = (long)(m0 + rloc) * lda + k0 + sqs * 8;
      }
      cp16(A + gofs, &As[(wave * 32 + i * 8) * 64]);
    }
#pragma unroll
    for (int i = 0; i < 4; i++) {
      const int rloc = wave * 32 + i * 8 + srow;
      const long gofs = (long)(n0 + rloc) * K + k0 + sqs * 8;
      cp16(Wt + gofs, &Bs[(wave * 32 + i * 8) * 64]);
    }
    __syncthreads();

    const int q4 = lane >> 4;     // 0..3
    const int r16 = lane & 15;
#pragma unroll
    for (int kk = 0; kk < 2; kk++) {
      short8 af[4], bf[4];
#pragma unroll
      for (int mi = 0; mi < 4; mi++) {
        const int row = wm * 64 + mi * 16 + r16;
        const int q = (kk * 4 + q4) ^ (row & 7);
        af[mi] = *(const short8*)&As[row * 64 + q * 8];
      }
#pragma unroll
      for (int ni = 0; ni < 4; ni++) {
        const int row = wn * 64 + ni * 16 + r16;
        const int q = (kk * 4 + q4) ^ (row & 7);
        bf[ni] = *(const short8*)&Bs[row * 64 + q * 8];
      }
#pragma unroll
      for (int mi = 0; mi < 4; mi++)
#pragma unroll
        for (int ni = 0; ni < 4; ni++)
          acc[mi][ni] = __builtin_amdgcn_mfma_f32_16x16x32_bf16(
              af[mi], bf[ni], acc[mi][ni], 0, 0, 0);
    }
    __syncthreads();
  }

  const int ccol = lane & 15;
  const int crow = (lane >> 4) * 4;
#pragma unroll
  for (int mi = 0; mi < 4; mi++) {
#pragma unroll
    for (int r = 0; r < 4; r++) {
      const int m = m0 + wm * 64 + mi * 16 + crow + r;
#pragma unroll
      for (int ni = 0; ni < 4; ni++) {
        const int n = n0 + wn * 64 + ni * 16 + ccol;
        const float v = acc[mi][ni][r];
        if (MODE == 6) {
          ((u16*)out0)[(long)m * ldo0 + n] = f2bf(v);
        }
      }
    }
  }
}

// fp32 -> bf16 cast, 4 elems/thread
__global__ __launch_bounds__(256) void cast_bf16(const float* __restrict__ in,
                                                 u16* __restrict__ out, int n4) {
  const long i = (long)blockIdx.x * 256 + threadIdx.x;
  if (i < n4) {
    const float4 v = ((const float4*)in)[i];
    ushort4 o;
    o.x = f2bf(v.x); o.y = f2bf(v.y); o.z = f2bf(v.z); o.w = f2bf(v.w);
    ((ushort4*)out)[i] = o;
  }
}

// W[K,N] fp32 -> Wt[N,K] bf16, 32x32 LDS tile transpose. K = OUT row length.
__global__ __launch_bounds__(256) void transp_bf16(const float* __restrict__ in,
                                                   u16* __restrict__ out, int K,
                                                   int N) {
  __shared__ float tile[32][33];
  const int tx = threadIdx.x & 31;
  const int ty = threadIdx.x >> 5;  // 0..7
  const long r0 = (long)blockIdx.y * 32;
  const long c0 = (long)blockIdx.x * 32;
#pragma unroll
  for (int r = 0; r < 4; r++)
    tile[ty + r * 8][tx] = in[(r0 + ty + r * 8) * N + c0 + tx];
  __syncthreads();
#pragma unroll
  for (int r = 0; r < 4; r++)
    out[(c0 + ty + r * 8) * K + r0 + tx] = f2bf(tile[tx][ty + r * 8]);
}

// All small precomputed folds in one launch (769 blocks, 4 waves each)
__global__ __launch_bounds__(256) void fold_all(
    const u16* __restrict__ GbT, const u16* __restrict__ FbT,
    const u16* __restrict__ Wt3, const float* __restrict__ centers,
    const float* __restrict__ fr_b2, const float* __restrict__ tc_b1,
    const float* __restrict__ tc_w2, const float* __restrict__ tc_b2,
    float* __restrict__ G2T, float* __restrict__ F2T, float* __restrict__ c2,
    float* __restrict__ S, float* __restrict__ bc) {
  const int b = blockIdx.x;
  const int wave = threadIdx.x >> 6, lane = threadIdx.x & 63;
  if (b < 256) {
    const int n = b * 4 + wave;
    float g[4] = {0.f, 0.f, 0.f, 0.f}, f[4] = {0.f, 0.f, 0.f, 0.f};
#pragma unroll
    for (int p = 0; p < 2; p++) {
      const int base = p * 512 + lane * 8;
      const short8 gv = *(const short8*)(GbT + (long)n * 1024 + base);
      const short8 fv = *(const short8*)(FbT + (long)n * 1024 + base);
#pragma unroll
      for (int e = 0; e < 8; e++) {
        const float ge = bf2f((u16)gv[e]), fe = bf2f((u16)fv[e]);
#pragma unroll
        for (int k = 0; k < 4; k++) {
          const float c = centers[k * 1024 + base + e];
          g[k] += ge * c;
          f[k] += fe * c;
        }
      }
    }
#pragma unroll
    for (int k = 0; k < 4; k++)
#pragma unroll
      for (int off = 32; off > 0; off >>= 1) {
        g[k] += __shfl_xor(g[k], off);
        f[k] += __shfl_xor(f[k], off);
      }
    if (lane == 0) {
#pragma unroll
      for (int k = 0; k < 4; k++) {
        G2T[n * 4 + k] = g[k];
        F2T[n * 4 + k] = f[k];
      }
    }
  } else if (b < 512) {
    const int j = (b - 256) * 4 + wave;
    float s = 0.f;
#pragma unroll
    for (int p = 0; p < 2; p++) {
      const int base = p * 512 + lane * 8;
      const short8 wv = *(const short8*)(Wt3 + (long)j * 1024 + base);
#pragma unroll
      for (int e = 0; e < 8; e++) s += fr_b2[base + e] * bf2f((u16)wv[e]);
    }
#pragma unroll
    for (int off = 32; off > 0; off >>= 1) s += __shfl_xor(s, off);
    if (lane == 0) c2[j] = s + tc_b1[j];
  } else if (b < 768) {
    const int d = (b - 512) * 4 + wave;
    const float* row = tc_w2 + (long)d * 1024;
    float s0 = 0.f, s1 = 0.f, s2 = 0.f, s3 = 0.f;
    for (int e = lane; e < 1024; e += 64) {
      const float w = row[e];
      s0 += w * centers[e];
      s1 += w * centers[1024 + e];
      s2 += w * centers[2048 + e];
      s3 += w * centers[3072 + e];
    }
#pragma unroll
    for (int off = 32; off > 0; off >>= 1) {
      s0 += __shfl_xor(s0, off);
      s1 += __shfl_xor(s1, off);
      s2 += __shfl_xor(s2, off);
      s3 += __shfl_xor(s3, off);
    }
    if (lane == 0) {
      S[d] = s0; S[1024 + d] = s1; S[2048 + d] = s2; S[3072 + d] = s3;
    }
  } else {
    const int k = wave;
    float s = 0.f;
    for (int e = lane; e < 1024; e += 64) s += tc_b2[e] * centers[k * 1024 + e];
#pragma unroll
    for (int off = 32; off > 0; off >>= 1) s += __shfl_xor(s, off);
    if (lane == 0) bc[k] = s;
  }
}

// w = softmax(h2 @ S^T + bc) over 4 centers; one wave per token -> w[t][0..3]
__global__ __launch_bounds__(256) void centers_kernel(
    const u16* __restrict__ h2, const float* __restrict__ S,
    const float* __restrict__ bc, float* __restrict__ wtok) {
  const int lane = threadIdx.x & 63;
  const int wave = threadIdx.x >> 6;
  const long t = (long)blockIdx.x * 4 + wave;
  const u16* row = h2 + t * 1024;
  float d0 = 0.f, d1 = 0.f, d2 = 0.f, d3 = 0.f;
#pragma unroll
  for (int j = 0; j < 2; j++) {
    const int dbase = j * 512 + lane * 8;
    const short8 v = *(const short8*)(row + dbase);
#pragma unroll
    for (int e = 0; e < 8; e++) {
      const float x = bf2f((u16)v[e]);
      const int d = dbase + e;
      d0 += x * S[d];
      d1 += x * S[1024 + d];
      d2 += x * S[2048 + d];
      d3 += x * S[3072 + d];
    }
  }
#pragma unroll
  for (int off = 32; off > 0; off >>= 1) {
    d0 += __shfl_xor(d0, off);
    d1 += __shfl_xor(d1, off);
    d2 += __shfl_xor(d2, off);
    d3 += __shfl_xor(d3, off);
  }
  if (lane == 0) {
    d0 += bc[0]; d1 += bc[1]; d2 += bc[2]; d3 += bc[3];
    const float mx = fmaxf(fmaxf(d0, d1), fmaxf(d2, d3));
    float e0 = expf(d0 - mx), e1 = expf(d1 - mx), e2 = expf(d2 - mx),
          e3 = expf(d3 - mx);
    const float inv = 1.0f / (e0 + e1 + e2 + e3);
    *(float4*)(wtok + t * 4) = (float4){e0 * inv, e1 * inv, e2 * inv, e3 * inv};
  }
}

extern "C" void kernel_launch(void* const* d_in, const int* in_sizes, int n_in,
                              void* d_out, int out_size, void* d_ws,
                              size_t ws_size, hipStream_t stream) {
  const float* queries = (const float*)d_in[0];
  const float* fr_w1 = (const float*)d_in[1];
  const float* fr_b1 = (const float*)d_in[2];
  const float* fr_w2 = (const float*)d_in[3];
  const float* fr_b2 = (const float*)d_in[4];
  const float* tc_w1 = (const float*)d_in[5];
  const float* tc_b1 = (const float*)d_in[6];
  const float* tc_w2 = (const float*)d_in[7];
  const float* tc_b2 = (const float*)d_in[8];
  const float* centers = (const float*)d_in[9];
  const float* fc_w1 = (const float*)d_in[10];
  const float* fc_b1 = (const float*)d_in[11];
  const float* fc_w2 = (const float*)d_in[12];
  const float* fc_b2 = (const float*)d_in[13];
  const float* g_w = (const float*)d_in[14];
  const float* g_b = (const float*)d_in[15];

  char* ws = (char*)d_ws;
  u16* Wt1 = (u16*)ws; ws += (size_t)7168 * 1024 * 2;   // fr_w1^T
  u16* Wt3 = (u16*)ws; ws += (size_t)1024 * 1024 * 2;   // tc_w1^T
  u16* Wt6 = (u16*)ws; ws += (size_t)1024 * 1024 * 2;   // fc_w2^T
  u16* WtJ = (u16*)ws; ws += (size_t)2048 * 1024 * 2;   // [fr_w2^T ; M2^T]
  u16* WtG2 = (u16*)ws; ws += (size_t)2048 * 1024 * 2;  // [g_w_top^T ; fc_w1_top^T]
  u16* Fw2b = (u16*)ws; ws += (size_t)1024 * 1024 * 2;  // fr_w2 bf16 (row-major)
  u16* GbT = (u16*)ws; ws += (size_t)1024 * 1024 * 2;   // g_w_bot^T bf16
  u16* FbT = (u16*)ws; ws += (size_t)1024 * 1024 * 2;   // fc_w1_bot^T bf16
  u16* Xb = (u16*)ws;  ws += (size_t)16384 * 1024 * 2;  // bf16 queries -> h2
  u16* h1 = (u16*)ws;  ws += (size_t)16384 * 1024 * 2;  // ring hidden -> fch
  u16* xrb = (u16*)ws; ws += (size_t)16384 * 1024 * 2;  // x_ring bf16
  float* xring = (float*)ws; ws += (size_t)16384 * 1024 * 4;  // x_ring f32
  float* wtok = (float*)ws; ws += (size_t)16384 * 4 * 4;      // softmax weights
  float* S = (float*)ws; ws += (size_t)4 * 1024 * 4;
  float* G2T = (float*)ws; ws += (size_t)1024 * 4 * 4;
  float* F2T = (float*)ws; ws += (size_t)1024 * 4 * 4;
  float* c2 = (float*)ws; ws += (size_t)1024 * 4;
  float* bc = (float*)ws; ws += 16;
  float* gate = (float*)d_out;  // gate f32 in d_out (read-then-overwrite)
  float* out = (float*)d_out;

  // allow 128 KB dynamic LDS on the big-tile GEMM (host-side, capture-safe)
  static bool attr_set = false;
  if (!attr_set) {
    attr_set = true;
    (void)hipFuncSetAttribute((const void*)gemm256<0, true>,
                              hipFuncAttributeMaxDynamicSharedMemorySize,
                              131072);
    (void)hipFuncSetAttribute((const void*)gemm256<7, false>,
                              hipFuncAttributeMaxDynamicSharedMemorySize,
                              131072);
    (void)hipFuncSetAttribute((const void*)gemm256<8, false>,
                              hipFuncAttributeMaxDynamicSharedMemorySize,
                              131072);
    (void)hipFuncSetAttribute((const void*)gemm256<4, false>,
                              hipFuncAttributeMaxDynamicSharedMemorySize,
                              131072);
  }

  // --- conversions / transposes ---
  cast_bf16<<<16384, 256, 0, stream>>>(queries, Xb, 16384 * 1024 / 4);
  cast_bf16<<<1024, 256, 0, stream>>>(fr_w2, Fw2b, 1024 * 1024 / 4);
  transp_bf16<<<dim3(32, 224), 256, 0, stream>>>(fr_w1, Wt1, 7168, 1024);
  transp_bf16<<<dim3(32, 32), 256, 0, stream>>>(tc_w1, Wt3, 1024, 1024);
  transp_bf16<<<dim3(32, 32), 256, 0, stream>>>(fc_w2, Wt6, 1024, 1024);
  transp_bf16<<<dim3(32, 32), 256, 0, stream>>>(fr_w2, WtJ, 1024, 1024);
  transp_bf16<<<dim3(32, 32), 256, 0, stream>>>(g_w, WtG2, 1024, 1024);
  transp_bf16<<<dim3(32, 32), 256, 0, stream>>>(fc_w1,
                                                WtG2 + (size_t)1024 * 1024,
                                                1024, 1024);
  transp_bf16<<<dim3(32, 32), 256, 0, stream>>>(g_w + (size_t)1024 * 1024, GbT,
                                                1024, 1024);
  transp_bf16<<<dim3(32, 32), 256, 0, stream>>>(fc_w1 + (size_t)1024 * 1024,
                                                FbT, 1024, 1024);
  // --- small folds: G2T/F2T, c2, S, bc ---
  fold_all<<<769, 256, 0, stream>>>(GbT, FbT, Wt3, centers, fr_b2, tc_b1,
                                    tc_w2, tc_b2, G2T, F2T, c2, S, bc);
  // --- M2^T = (fr_w2 @ tc_w1)^T via GEMM: C[j][i] = sum_e Wt3[j][e]*Fw2b[i][e]
  gemm128<6, false><<<dim3(8, 8), 256, 0, stream>>>(
      Wt3, 1024, Fw2b, 1024, nullptr, nullptr, WtJ + (size_t)1024 * 1024, 1024,
      nullptr, nullptr, nullptr, nullptr, nullptr);

  // --- main chain (256x256 prefetch-pipelined GEMMs) ---
  // fr1: h1 = gelu(ring_gather(x) @ fr_w1 + fr_b1)
  gemm256<0, true><<<dim3(4, 64), 512, 131072, stream>>>(
      Xb, 0, Wt1, 7168, fr_b1, nullptr, h1, 1024, nullptr, nullptr, nullptr,
      nullptr, nullptr);
  // joint1: x_ring (f32 + bf16) and h2 in one pass over h1
  gemm256<7, false><<<dim3(8, 64), 512, 131072, stream>>>(
      h1, 1024, WtJ, 1024, fr_b2, c2, xrb, 1024, xring, Xb, nullptr, nullptr,
      nullptr);
  // w = softmax(h2 @ S^T + bc)
  centers_kernel<<<4096, 256, 0, stream>>>(Xb, S, bc, wtok);
  // joint2: gate -> d_out, fch -> h1 (w-corrections in epilogue)
  gemm256<8, false><<<dim3(8, 64), 512, 131072, stream>>>(
      xrb, 1024, WtG2, 1024, g_b, fc_b1, gate, 1024, h1, nullptr, wtok, G2T,
      F2T);
  // fc2 + final mix: out = gate*(fch @ fc_w2 + fc_b2) + (1-gate)*x_ring
  gemm256<4, false><<<dim3(4, 64), 512, 131072, stream>>>(
      h1, 1024, Wt6, 1024, fc_b2, nullptr, out, 1024, nullptr, nullptr, gate,
      xring, nullptr);
}

// Round 4
// 770.048 us; speedup vs baseline: 1.1218x; 1.0333x over previous
//
#include <hip/hip_runtime.h>
#include <hip/hip_bf16.h>
#include <math.h>

typedef unsigned short u16;
typedef __attribute__((ext_vector_type(8))) short short8;   // 8 bf16 (4 VGPRs)
typedef __attribute__((ext_vector_type(4))) float f32x4;    // MFMA C/D frag

// Problem constants: B=8, N=2048, D=DC=1024, K_centers=4, M = B*N = 16384.
//
// R4 algebra (no fus2, no tc2, no tc1 as separate GEMMs):
//   h1    = gelu(ring_gather(x) @ fr_w1 + fr_b1)                 [240 GF]
//   joint1 over h1 (Nout=2048, K=1024):                          [68.7 GF]
//     x_ring = h1 @ fr_w2 + fr_b2          (f32 + bf16 copies)
//     h2     = gelu(h1 @ M2 + c2),  M2 = fr_w2@tc_w1 (precomputed GEMM),
//                                   c2 = fr_b2@tc_w1 + tc_b1
//   w = softmax(h2 @ S^T + bc),  S = centers@tc_w2^T (folded tc2) [small]
//   joint2 over x_ring_bf16 (Nout=2048, K=1024):                 [68.7 GF]
//     gate = sigmoid(x_ring@g_w_top  + w@G2 + g_b)   G2 = centers@g_w_bot
//     fch  = gelu  (x_ring@fc_w1_top + w@F2 + fc_b1) F2 = centers@fc_w1_bot
//   out = gate*(fch @ fc_w2 + fc_b2) + (1-gate)*x_ring           [34 GF]
//
// R8: staging-address hoisting. R5-R7 all measured ~2800 cyc/step with
// VALUBusy 28% (~830 cyc/step) -- the per-step 64-bit gofs recompute
// (4x mul chains + gather switch) sat serialized at the step top. Now the
// stage sources are loop-carried pointers bumped +64B/step; the gather
// segment recompute happens only every 32 steps (uniform branch). Body
// order: ds_reads first, cheap staging second, R7 ladder unchanged.

__device__ __forceinline__ float bf2f(u16 b) {
  return __uint_as_float(((unsigned int)b) << 16);
}
__device__ __forceinline__ u16 f2bf(float f) {
  unsigned int u = __float_as_uint(f);
  u += 0x7FFFu + ((u >> 16) & 1u);   // round-to-nearest-even (finite inputs)
  return (u16)(u >> 16);
}
__device__ __forceinline__ float gelu_exact(float x) {
  return 0.5f * x * (1.0f + erff(x * 0.70710678118654752f));
}

// async 16B/lane global->LDS. LDS dest is wave-uniform base + lane*16.
__device__ __forceinline__ void cp16(const void* g, void* l) {
  __builtin_amdgcn_global_load_lds(
      (const __attribute__((address_space(1))) unsigned int*)g,
      (__attribute__((address_space(3))) unsigned int*)l, 16, 0, 0);
}

// ---------------------------------------------------------------------------
// gemm256: C[M,Nout] = A[M,K](bf16) @ Wt[Nout,K]^T(bf16)
// 256x256 tile, BK=32, ring-4 LDS, 512 threads (8 waves 2x4),
// per-wave 128x64 out = acc[8][4] of 16x16x32 MFMA.
//
// LDS layout per buffer (A 16KB then B 16KB): paired-row swizzle (R5-R7).
// vmcnt ledger (4 cp16/step, staged 3 ahead): enter iter s with {s+2:4};
// issue stage(s+3) -> 8; vmcnt(4) (after MFMA, before barrier) confirms
// s+2. lgkm ledger (DS FIFO): enter with 6 (prev prefetch); +6 remainder
// (af[2..7] of slot s) -> 12; +6 prefetch (slot s+1) -> 18; lgkm(12)=
// prev-pf done; lgkm(10)=af2,3; lgkm(8)=af4,5; lgkm(6)=af6,7; exit 6.
// Staging pointers: pA0/pA1/pB0/pB1 point at source for target step
// t = min(s+3, nt-1); advance +32 elems iff s+4 <= nt-1; GATHER recomputes
// from scratch when (s+4)&31 == 0 (k crosses a 1024 segment boundary).
// ---------------------------------------------------------------------------
template <int MODE, bool GATHER>
__global__ __launch_bounds__(512) void gemm256(
    const u16* __restrict__ A, int lda, const u16* __restrict__ Wt, int K,
    const float* __restrict__ bias, const float* __restrict__ bias2,
    void* __restrict__ out0, int ldo0, void* __restrict__ out1,
    void* __restrict__ out2, const float* __restrict__ p0,
    const float* __restrict__ p1, const float* __restrict__ p2) {
  extern __shared__ __align__(16) char sm[];   // 4 bufs * 32 KB = 128 KB
  const int tid = threadIdx.x;
  const int lane = tid & 63;
  const int wave = tid >> 6;     // 0..7
  const int wm = wave >> 2;      // wave row in 2x4
  const int wn = wave & 3;       // wave col

  // ---- XCD-aware block swizzle (gridDim.y divisible by 8) ----
  const unsigned linear = blockIdx.y * gridDim.x + blockIdx.x;
  const unsigned xcd = linear & 7u;
  const unsigned pos = linear >> 3;
  const unsigned bx = pos % gridDim.x;
  const unsigned by = xcd * (gridDim.y >> 3) + pos / gridDim.x;
  const int m0 = by * 256;
  const int n0 = bx * 256;

  // staging (write-side) lane constants: lane covers (sr = chunk*8 + sl, qq)
  const int sl = lane >> 3;           // 0..7 superrow within 1KB chunk
  const int qqs = (lane & 7) ^ sl;    // pre-inverse-swizzled content slot
  const int rowoff = sl * 2 + (qqs >> 2);  // row within 16-row chunk
  const int colq = qqs & 3;                // k-quad (8 bf16) within BK=32

  // ds_read (read-side) lane constants
  const int r16 = lane & 15, q4 = lane >> 4;
  const int qqr = (((r16 & 1) << 2) | q4) ^ (r16 >> 1);
  const int laneA = wm * 8192 + (r16 >> 1) * 128 + qqr * 16;  // bytes
  const int laneB = wn * 4096 + (r16 >> 1) * 128 + qqr * 16;

  const int nt = K >> 5;   // K/32 steps (even, >=4 for all call sites)

  f32x4 acc[8][4];
#pragma unroll
  for (int i = 0; i < 8; i++)
#pragma unroll
    for (int j = 0; j < 4; j++) acc[i][j] = (f32x4){0.f, 0.f, 0.f, 0.f};

  // global source address for staging target step t, chunk-half i (0/1)
  auto a_src = [&](int t, int i) -> const u16* {
    const int chunk = wave + i * 8;        // 0..15 (1KB each)
    const int row = chunk * 16 + rowoff;   // 0..255 tile row
    if (GATHER) {
      const int kg = t * 32 + colq * 8;    // global k (seg-uniform per step)
      const int seg = kg >> 10;
      int shift;
      switch (seg) {
        case 0: shift = 1; break;
        case 1: shift = -1; break;
        case 2: shift = 0; break;
        case 3: shift = 2; break;
        case 4: shift = -2; break;
        case 5: shift = 4; break;
        default: shift = -4; break;
      }
      const int m = m0 + row;
      const int b = m >> 11;               // N = 2048 = 2^11
      const int nsrc = ((m & 2047) - shift) & 2047;
      return A + (long)((b << 11) | nsrc) * 1024 + (kg & 1023);
    }
    return A + (long)(m0 + row) * lda + t * 32 + colq * 8;
  };
  auto b_src = [&](int t, int i) -> const u16* {
    const int chunk = wave + i * 8;
    const int row = chunk * 16 + rowoff;
    return Wt + (long)(n0 + row) * K + t * 32 + colq * 8;
  };

  // prefetch first-group frags of step s into (pbf, paf01)
  auto prefetch = [&](int s, short8 (&pbf)[4], short8 (&paf01)[2]) {
    const char* base = sm + ((s & 3) << 15);
#pragma unroll
    for (int ni = 0; ni < 4; ni++)
      pbf[ni] = *(const short8*)(base + 16384 + laneB + ni * 1024);
#pragma unroll
    for (int mi = 0; mi < 2; mi++)
      paf01[mi] = *(const short8*)(base + laneA + mi * 1024);
  };

  // loop-carried staging pointers (source for target t = min(s+3, nt-1))
  const u16 *pA0, *pA1, *pB0, *pB1;

  auto body = [&](int s, short8 (&cbf)[4], short8 (&caf01)[2],
                  short8 (&nbf)[4], short8 (&naf01)[2]) {
    const char* abase = sm + ((s & 3) << 15);
    // ---- ds_reads first: remainder A-frags of slot s, then prefetch s+1
    short8 afr[6];
#pragma unroll
    for (int j = 0; j < 6; j++)   // remainder A-frags: mi = j+2
      afr[j] = *(const short8*)(abase + laneA + (j + 2) * 1024);
    prefetch(s + 1, nbf, naf01);

    // ---- cheap staging: 4 cp16 off loop-carried pointers
    const int sofs = ((s + 3) & 3) << 15;
    cp16(pA0, sm + sofs + wave * 1024);
    cp16(pA1, sm + sofs + (wave + 8) * 1024);
    cp16(pB0, sm + sofs + 16384 + wave * 1024);
    cp16(pB1, sm + sofs + 16384 + (wave + 8) * 1024);
    if (s + 4 <= nt - 1) {
      if (GATHER && (((s + 4) & 31) == 0)) {
        pA0 = a_src(s + 4, 0);
        pA1 = a_src(s + 4, 1);
      } else {
        pA0 += 32;
        pA1 += 32;
      }
      pB0 += 32;
      pB1 += 32;
    }

    asm volatile("s_waitcnt lgkmcnt(12)" ::: "memory");  // prev prefetch done
    __builtin_amdgcn_sched_barrier(0);
    __builtin_amdgcn_s_setprio(1);
#pragma unroll
    for (int mi = 0; mi < 2; mi++)
#pragma unroll
      for (int ni = 0; ni < 4; ni++)
        acc[mi][ni] = __builtin_amdgcn_mfma_f32_16x16x32_bf16(
            caf01[mi], cbf[ni], acc[mi][ni], 0, 0, 0);

    asm volatile("s_waitcnt lgkmcnt(10)" ::: "memory");  // afr[0],afr[1]
    __builtin_amdgcn_sched_barrier(0);
#pragma unroll
    for (int j = 0; j < 2; j++)
#pragma unroll
      for (int ni = 0; ni < 4; ni++)
        acc[2 + j][ni] = __builtin_amdgcn_mfma_f32_16x16x32_bf16(
            afr[j], cbf[ni], acc[2 + j][ni], 0, 0, 0);

    asm volatile("s_waitcnt lgkmcnt(8)" ::: "memory");   // afr[2],afr[3]
    __builtin_amdgcn_sched_barrier(0);
#pragma unroll
    for (int j = 0; j < 2; j++)
#pragma unroll
      for (int ni = 0; ni < 4; ni++)
        acc[4 + j][ni] = __builtin_amdgcn_mfma_f32_16x16x32_bf16(
            afr[2 + j], cbf[ni], acc[4 + j][ni], 0, 0, 0);

    asm volatile("s_waitcnt lgkmcnt(6)" ::: "memory");   // afr[4],afr[5]
    __builtin_amdgcn_sched_barrier(0);
#pragma unroll
    for (int j = 0; j < 2; j++)
#pragma unroll
      for (int ni = 0; ni < 4; ni++)
        acc[6 + j][ni] = __builtin_amdgcn_mfma_f32_16x16x32_bf16(
            afr[4 + j], cbf[ni], acc[6 + j][ni], 0, 0, 0);
    __builtin_amdgcn_s_setprio(0);

    asm volatile("s_waitcnt vmcnt(4)" ::: "memory");  // slot s+2 landed (mine)
    __builtin_amdgcn_s_barrier();                     // publish s+1, s+2
  };

  // ---- prologue: stage 0,1,2; confirm 0,1; init pointers at t=3 ----
#pragma unroll
  for (int t = 0; t < 3; t++) {
    cp16(a_src(t, 0), sm + t * 32768 + wave * 1024);
    cp16(a_src(t, 1), sm + t * 32768 + (wave + 8) * 1024);
    cp16(b_src(t, 0), sm + t * 32768 + 16384 + wave * 1024);
    cp16(b_src(t, 1), sm + t * 32768 + 16384 + (wave + 8) * 1024);
  }
  pA0 = a_src(3, 0); pA1 = a_src(3, 1);
  pB0 = b_src(3, 0); pB1 = b_src(3, 1);
  asm volatile("s_waitcnt vmcnt(4)" ::: "memory");  // slots 0,1 landed
  __builtin_amdgcn_s_barrier();                     // published

  short8 bfA[4], afA[2], bfB[4], afB[2];
  prefetch(0, bfA, afA);   // 6 DS outstanding entering the loop

  for (int s = 0; s < nt; s += 2) {
    body(s, bfA, afA, bfB, afB);
    body(s + 1, bfB, afB, bfA, afA);
  }
  asm volatile("s_waitcnt vmcnt(0) lgkmcnt(0)" ::: "memory");  // drain tail

  // epilogue: C/D layout col = lane&15, row = (lane>>4)*4 + reg
  const int ccol = lane & 15;
  const int crow = (lane >> 4) * 4;
#pragma unroll
  for (int mi = 0; mi < 8; mi++) {
#pragma unroll
    for (int r = 0; r < 4; r++) {
      const int m = m0 + wm * 128 + mi * 16 + crow + r;
      float4 wrow;
      if (MODE == 8) wrow = *(const float4*)(p0 + (size_t)m * 4);
#pragma unroll
      for (int ni = 0; ni < 4; ni++) {
        const int n = n0 + wn * 64 + ni * 16 + ccol;
        const float v = acc[mi][ni][r];
        if (MODE == 0) {
          ((u16*)out0)[(long)m * ldo0 + n] = f2bf(gelu_exact(v + bias[n]));
        } else if (MODE == 4) {
          const float g = p0[(long)m * 1024 + n];
          const float xr = p1[(long)m * 1024 + n];
          ((float*)out0)[(long)m * ldo0 + n] =
              g * (v + bias[n]) + (1.0f - g) * xr;
        } else if (MODE == 6) {
          ((u16*)out0)[(long)m * ldo0 + n] = f2bf(v);
        } else if (MODE == 7) {
          if (n < 1024) {
            const float s = v + bias[n];
            ((float*)out1)[(long)m * 1024 + n] = s;
            ((u16*)out0)[(long)m * 1024 + n] = f2bf(s);
          } else {
            const int nn = n - 1024;
            ((u16*)out2)[(long)m * 1024 + nn] = f2bf(gelu_exact(v + bias2[nn]));
          }
        } else if (MODE == 8) {
          if (n < 1024) {
            const float4 g2 = *(const float4*)(p1 + (size_t)n * 4);
            const float s = v + bias[n] + wrow.x * g2.x + wrow.y * g2.y +
                            wrow.z * g2.z + wrow.w * g2.w;
            ((float*)out0)[(long)m * 1024 + n] = 1.0f / (1.0f + expf(-s));
          } else {
            const int nn = n - 1024;
            const float4 f2 = *(const float4*)(p2 + (size_t)nn * 4);
            const float s = v + bias2[nn] + wrow.x * f2.x + wrow.y * f2.y +
                            wrow.z * f2.z + wrow.w * f2.w;
            ((u16*)out1)[(long)m * 1024 + nn] = f2bf(gelu_exact(s));
          }
        }
      }
    }
  }
}

// ---------------------------------------------------------------------------
// gemm128 (m97-class, kept only for the small M2 precompute: M=1024, MODE 6)
// ---------------------------------------------------------------------------
template <int MODE, bool GATHER>
__global__ __launch_bounds__(256) void gemm128(
    const u16* __restrict__ A, int lda, const u16* __restrict__ Wt, int K,
    const float* __restrict__ bias, const float* __restrict__ bias2,
    void* __restrict__ out0, int ldo0, void* __restrict__ out1,
    void* __restrict__ out2, const float* __restrict__ p0,
    const float* __restrict__ p1, const float* __restrict__ p2) {
  __shared__ __align__(16) u16 As[128 * 64];
  __shared__ __align__(16) u16 Bs[128 * 64];

  const int tid = threadIdx.x;
  const int lane = tid & 63;
  const int wave = tid >> 6;     // 0..3
  const int wm = wave >> 1;      // wave row in 2x2
  const int wn = wave & 1;       // wave col

  const unsigned linear = blockIdx.y * gridDim.x + blockIdx.x;
  const unsigned xcd = linear & 7u;
  const unsigned pos = linear >> 3;
  const unsigned bx = pos % gridDim.x;
  const unsigned by = xcd * (gridDim.y >> 3) + pos / gridDim.x;
  const int m0 = by * 128;
  const int n0 = bx * 128;

  const int srow = lane >> 3;    // 0..7: row within an 8-row staging chunk
  const int sq = lane & 7;       // quad (16B) within a 128B row
  const int sqs = sq ^ srow;     // swizzled global quad

  f32x4 acc[4][4];
#pragma unroll
  for (int i = 0; i < 4; i++)
#pragma unroll
    for (int j = 0; j < 4; j++) acc[i][j] = (f32x4){0.f, 0.f, 0.f, 0.f};

  for (int k0 = 0; k0 < K; k0 += 64) {
#pragma unroll
    for (int i = 0; i < 4; i++) {
      const int rloc = wave * 32 + i * 8 + srow;   // 0..127
      const long gofs = (long)(m0 + rloc) * lda + k0 + sqs * 8;
      cp16(A + gofs, &As[(wave * 32 + i * 8) * 64]);
    }
#pragma unroll
    for (int i = 0; i < 4; i++) {
      const int rloc = wave * 32 + i * 8 + srow;
      const long gofs = (long)(n0 + rloc) * K + k0 + sqs * 8;
      cp16(Wt + gofs, &Bs[(wave * 32 + i * 8) * 64]);
    }
    __syncthreads();

    const int q4 = lane >> 4;     // 0..3
    const int r16 = lane & 15;
#pragma unroll
    for (int kk = 0; kk < 2; kk++) {
      short8 af[4], bf[4];
#pragma unroll
      for (int mi = 0; mi < 4; mi++) {
        const int row = wm * 64 + mi * 16 + r16;
        const int q = (kk * 4 + q4) ^ (row & 7);
        af[mi] = *(const short8*)&As[row * 64 + q * 8];
      }
#pragma unroll
      for (int ni = 0; ni < 4; ni++) {
        const int row = wn * 64 + ni * 16 + r16;
        const int q = (kk * 4 + q4) ^ (row & 7);
        bf[ni] = *(const short8*)&Bs[row * 64 + q * 8];
      }
#pragma unroll
      for (int mi = 0; mi < 4; mi++)
#pragma unroll
        for (int ni = 0; ni < 4; ni++)
          acc[mi][ni] = __builtin_amdgcn_mfma_f32_16x16x32_bf16(
              af[mi], bf[ni], acc[mi][ni], 0, 0, 0);
    }
    __syncthreads();
  }

  const int ccol = lane & 15;
  const int crow = (lane >> 4) * 4;
#pragma unroll
  for (int mi = 0; mi < 4; mi++) {
#pragma unroll
    for (int r = 0; r < 4; r++) {
      const int m = m0 + wm * 64 + mi * 16 + crow + r;
#pragma unroll
      for (int ni = 0; ni < 4; ni++) {
        const int n = n0 + wn * 64 + ni * 16 + ccol;
        const float v = acc[mi][ni][r];
        if (MODE == 6) {
          ((u16*)out0)[(long)m * ldo0 + n] = f2bf(v);
        }
      }
    }
  }
}

// fp32 -> bf16 cast, 4 elems/thread
__global__ __launch_bounds__(256) void cast_bf16(const float* __restrict__ in,
                                                 u16* __restrict__ out, int n4) {
  const long i = (long)blockIdx.x * 256 + threadIdx.x;
  if (i < n4) {
    const float4 v = ((const float4*)in)[i];
    ushort4 o;
    o.x = f2bf(v.x); o.y = f2bf(v.y); o.z = f2bf(v.z); o.w = f2bf(v.w);
    ((ushort4*)out)[i] = o;
  }
}

// W[K,N] fp32 -> Wt[N,K] bf16, 32x32 LDS tile transpose. K = OUT row length.
__global__ __launch_bounds__(256) void transp_bf16(const float* __restrict__ in,
                                                   u16* __restrict__ out, int K,
                                                   int N) {
  __shared__ float tile[32][33];
  const int tx = threadIdx.x & 31;
  const int ty = threadIdx.x >> 5;  // 0..7
  const long r0 = (long)blockIdx.y * 32;
  const long c0 = (long)blockIdx.x * 32;
#pragma unroll
  for (int r = 0; r < 4; r++)
    tile[ty + r * 8][tx] = in[(r0 + ty + r * 8) * N + c0 + tx];
  __syncthreads();
#pragma unroll
  for (int r = 0; r < 4; r++)
    out[(c0 + ty + r * 8) * K + r0 + tx] = f2bf(tile[tx][ty + r * 8]);
}

// seven fused 1024x1024 fp32->bf16 transposes (one launch, blockIdx.z picks)
__global__ __launch_bounds__(256) void transp7(
    const float* __restrict__ s0, const float* __restrict__ s1,
    const float* __restrict__ s2, const float* __restrict__ s3,
    const float* __restrict__ s4, const float* __restrict__ s5,
    const float* __restrict__ s6, u16* __restrict__ d0, u16* __restrict__ d1,
    u16* __restrict__ d2, u16* __restrict__ d3, u16* __restrict__ d4,
    u16* __restrict__ d5, u16* __restrict__ d6) {
  __shared__ float tile[32][33];
  const float* in;
  u16* out;
  switch (blockIdx.z) {
    case 0: in = s0; out = d0; break;
    case 1: in = s1; out = d1; break;
    case 2: in = s2; out = d2; break;
    case 3: in = s3; out = d3; break;
    case 4: in = s4; out = d4; break;
    case 5: in = s5; out = d5; break;
    default: in = s6; out = d6; break;
  }
  const int tx = threadIdx.x & 31;
  const int ty = threadIdx.x >> 5;  // 0..7
  const long r0 = (long)blockIdx.y * 32;
  const long c0 = (long)blockIdx.x * 32;
#pragma unroll
  for (int r = 0; r < 4; r++)
    tile[ty + r * 8][tx] = in[(r0 + ty + r * 8) * 1024 + c0 + tx];
  __syncthreads();
#pragma unroll
  for (int r = 0; r < 4; r++)
    out[(c0 + ty + r * 8) * 1024 + r0 + tx] = f2bf(tile[tx][ty + r * 8]);
}

// All small precomputed folds in one launch (769 blocks, 4 waves each)
__global__ __launch_bounds__(256) void fold_all(
    const u16* __restrict__ GbT, const u16* __restrict__ FbT,
    const u16* __restrict__ Wt3, const float* __restrict__ centers,
    const float* __restrict__ fr_b2, const float* __restrict__ tc_b1,
    const float* __restrict__ tc_w2, const float* __restrict__ tc_b2,
    float* __restrict__ G2T, float* __restrict__ F2T, float* __restrict__ c2,
    float* __restrict__ S, float* __restrict__ bc) {
  const int b = blockIdx.x;
  const int wave = threadIdx.x >> 6, lane = threadIdx.x & 63;
  if (b < 256) {
    const int n = b * 4 + wave;
    float g[4] = {0.f, 0.f, 0.f, 0.f}, f[4] = {0.f, 0.f, 0.f, 0.f};
#pragma unroll
    for (int p = 0; p < 2; p++) {
      const int base = p * 512 + lane * 8;
      const short8 gv = *(const short8*)(GbT + (long)n * 1024 + base);
      const short8 fv = *(const short8*)(FbT + (long)n * 1024 + base);
#pragma unroll
      for (int e = 0; e < 8; e++) {
        const float ge = bf2f((u16)gv[e]), fe = bf2f((u16)fv[e]);
#pragma unroll
        for (int k = 0; k < 4; k++) {
          const float c = centers[k * 1024 + base + e];
          g[k] += ge * c;
          f[k] += fe * c;
        }
      }
    }
#pragma unroll
    for (int k = 0; k < 4; k++)
#pragma unroll
      for (int off = 32; off > 0; off >>= 1) {
        g[k] += __shfl_xor(g[k], off);
        f[k] += __shfl_xor(f[k], off);
      }
    if (lane == 0) {
#pragma unroll
      for (int k = 0; k < 4; k++) {
        G2T[n * 4 + k] = g[k];
        F2T[n * 4 + k] = f[k];
      }
    }
  } else if (b < 512) {
    const int j = (b - 256) * 4 + wave;
    float s = 0.f;
#pragma unroll
    for (int p = 0; p < 2; p++) {
      const int base = p * 512 + lane * 8;
      const short8 wv = *(const short8*)(Wt3 + (long)j * 1024 + base);
#pragma unroll
      for (int e = 0; e < 8; e++) s += fr_b2[base + e] * bf2f((u16)wv[e]);
    }
#pragma unroll
    for (int off = 32; off > 0; off >>= 1) s += __shfl_xor(s, off);
    if (lane == 0) c2[j] = s + tc_b1[j];
  } else if (b < 768) {
    const int d = (b - 512) * 4 + wave;
    const float* row = tc_w2 + (long)d * 1024;
    float s0 = 0.f, s1 = 0.f, s2 = 0.f, s3 = 0.f;
    for (int e = lane; e < 1024; e += 64) {
      const float w = row[e];
      s0 += w * centers[e];
      s1 += w * centers[1024 + e];
      s2 += w * centers[2048 + e];
      s3 += w * centers[3072 + e];
    }
#pragma unroll
    for (int off = 32; off > 0; off >>= 1) {
      s0 += __shfl_xor(s0, off);
      s1 += __shfl_xor(s1, off);
      s2 += __shfl_xor(s2, off);
      s3 += __shfl_xor(s3, off);
    }
    if (lane == 0) {
      S[d] = s0; S[1024 + d] = s1; S[2048 + d] = s2; S[3072 + d] = s3;
    }
  } else {
    const int k = wave;
    float s = 0.f;
    for (int e = lane; e < 1024; e += 64) s += tc_b2[e] * centers[k * 1024 + e];
#pragma unroll
    for (int off = 32; off > 0; off >>= 1) s += __shfl_xor(s, off);
    if (lane == 0) bc[k] = s;
  }
}

// w = softmax(h2 @ S^T + bc) over 4 centers; one wave per token -> w[t][0..3]
__global__ __launch_bounds__(256) void centers_kernel(
    const u16* __restrict__ h2, const float* __restrict__ S,
    const float* __restrict__ bc, float* __restrict__ wtok) {
  const int lane = threadIdx.x & 63;
  const int wave = threadIdx.x >> 6;
  const long t = (long)blockIdx.x * 4 + wave;
  const u16* row = h2 + t * 1024;
  float d0 = 0.f, d1 = 0.f, d2 = 0.f, d3 = 0.f;
#pragma unroll
  for (int j = 0; j < 2; j++) {
    const int dbase = j * 512 + lane * 8;
    const short8 v = *(const short8*)(row + dbase);
#pragma unroll
    for (int e = 0; e < 8; e++) {
      const float x = bf2f((u16)v[e]);
      const int d = dbase + e;
      d0 += x * S[d];
      d1 += x * S[1024 + d];
      d2 += x * S[2048 + d];
      d3 += x * S[3072 + d];
    }
  }
#pragma unroll
  for (int off = 32; off > 0; off >>= 1) {
    d0 += __shfl_xor(d0, off);
    d1 += __shfl_xor(d1, off);
    d2 += __shfl_xor(d2, off);
    d3 += __shfl_xor(d3, off);
  }
  if (lane == 0) {
    d0 += bc[0]; d1 += bc[1]; d2 += bc[2]; d3 += bc[3];
    const float mx = fmaxf(fmaxf(d0, d1), fmaxf(d2, d3));
    float e0 = expf(d0 - mx), e1 = expf(d1 - mx), e2 = expf(d2 - mx),
          e3 = expf(d3 - mx);
    const float inv = 1.0f / (e0 + e1 + e2 + e3);
    *(float4*)(wtok + t * 4) = (float4){e0 * inv, e1 * inv, e2 * inv, e3 * inv};
  }
}

extern "C" void kernel_launch(void* const* d_in, const int* in_sizes, int n_in,
                              void* d_out, int out_size, void* d_ws,
                              size_t ws_size, hipStream_t stream) {
  const float* queries = (const float*)d_in[0];
  const float* fr_w1 = (const float*)d_in[1];
  const float* fr_b1 = (const float*)d_in[2];
  const float* fr_w2 = (const float*)d_in[3];
  const float* fr_b2 = (const float*)d_in[4];
  const float* tc_w1 = (const float*)d_in[5];
  const float* tc_b1 = (const float*)d_in[6];
  const float* tc_w2 = (const float*)d_in[7];
  const float* tc_b2 = (const float*)d_in[8];
  const float* centers = (const float*)d_in[9];
  const float* fc_w1 = (const float*)d_in[10];
  const float* fc_b1 = (const float*)d_in[11];
  const float* fc_w2 = (const float*)d_in[12];
  const float* fc_b2 = (const float*)d_in[13];
  const float* g_w = (const float*)d_in[14];
  const float* g_b = (const float*)d_in[15];

  char* ws = (char*)d_ws;
  u16* Wt1 = (u16*)ws; ws += (size_t)7168 * 1024 * 2;   // fr_w1^T
  u16* Wt3 = (u16*)ws; ws += (size_t)1024 * 1024 * 2;   // tc_w1^T
  u16* Wt6 = (u16*)ws; ws += (size_t)1024 * 1024 * 2;   // fc_w2^T
  u16* WtJ = (u16*)ws; ws += (size_t)2048 * 1024 * 2;   // [fr_w2^T ; M2^T]
  u16* WtG2 = (u16*)ws; ws += (size_t)2048 * 1024 * 2;  // [g_w_top^T ; fc_w1_top^T]
  u16* Fw2b = (u16*)ws; ws += (size_t)1024 * 1024 * 2;  // fr_w2 bf16 (row-major)
  u16* GbT = (u16*)ws; ws += (size_t)1024 * 1024 * 2;   // g_w_bot^T bf16
  u16* FbT = (u16*)ws; ws += (size_t)1024 * 1024 * 2;   // fc_w1_bot^T bf16
  u16* Xb = (u16*)ws;  ws += (size_t)16384 * 1024 * 2;  // bf16 queries -> h2
  u16* h1 = (u16*)ws;  ws += (size_t)16384 * 1024 * 2;  // ring hidden -> fch
  u16* xrb = (u16*)ws; ws += (size_t)16384 * 1024 * 2;  // x_ring bf16
  float* xring = (float*)ws; ws += (size_t)16384 * 1024 * 4;  // x_ring f32
  float* wtok = (float*)ws; ws += (size_t)16384 * 4 * 4;      // softmax weights
  float* S = (float*)ws; ws += (size_t)4 * 1024 * 4;
  float* G2T = (float*)ws; ws += (size_t)1024 * 4 * 4;
  float* F2T = (float*)ws; ws += (size_t)1024 * 4 * 4;
  float* c2 = (float*)ws; ws += (size_t)1024 * 4;
  float* bc = (float*)ws; ws += 16;
  float* gate = (float*)d_out;  // gate f32 in d_out (read-then-overwrite)
  float* out = (float*)d_out;

  // allow 128 KB dynamic LDS on the big-tile GEMM (host-side, capture-safe)
  static bool attr_set = false;
  if (!attr_set) {
    attr_set = true;
    (void)hipFuncSetAttribute((const void*)gemm256<0, true>,
                              hipFuncAttributeMaxDynamicSharedMemorySize,
                              131072);
    (void)hipFuncSetAttribute((const void*)gemm256<7, false>,
                              hipFuncAttributeMaxDynamicSharedMemorySize,
                              131072);
    (void)hipFuncSetAttribute((const void*)gemm256<8, false>,
                              hipFuncAttributeMaxDynamicSharedMemorySize,
                              131072);
    (void)hipFuncSetAttribute((const void*)gemm256<4, false>,
                              hipFuncAttributeMaxDynamicSharedMemorySize,
                              131072);
  }

  // --- conversions / transposes ---
  cast_bf16<<<16384, 256, 0, stream>>>(queries, Xb, 16384 * 1024 / 4);
  cast_bf16<<<1024, 256, 0, stream>>>(fr_w2, Fw2b, 1024 * 1024 / 4);
  transp_bf16<<<dim3(32, 224), 256, 0, stream>>>(fr_w1, Wt1, 7168, 1024);
  transp7<<<dim3(32, 32, 7), 256, 0, stream>>>(
      tc_w1, fc_w2, fr_w2, g_w, fc_w1, g_w + (size_t)1024 * 1024,
      fc_w1 + (size_t)1024 * 1024, Wt3, Wt6, WtJ, WtG2,
      WtG2 + (size_t)1024 * 1024, GbT, FbT);
  // --- small folds: G2T/F2T, c2, S, bc ---
  fold_all<<<769, 256, 0, stream>>>(GbT, FbT, Wt3, centers, fr_b2, tc_b1,
                                    tc_w2, tc_b2, G2T, F2T, c2, S, bc);
  // --- M2^T = (fr_w2 @ tc_w1)^T via GEMM: C[j][i] = sum_e Wt3[j][e]*Fw2b[i][e]
  gemm128<6, false><<<dim3(8, 8), 256, 0, stream>>>(
      Wt3, 1024, Fw2b, 1024, nullptr, nullptr, WtJ + (size_t)1024 * 1024, 1024,
      nullptr, nullptr, nullptr, nullptr, nullptr);

  // --- main chain (256x256 pointer-hoisted pipelined GEMMs) ---
  // fr1: h1 = gelu(ring_gather(x) @ fr_w1 + fr_b1)
  gemm256<0, true><<<dim3(4, 64), 512, 131072, stream>>>(
      Xb, 0, Wt1, 7168, fr_b1, nullptr, h1, 1024, nullptr, nullptr, nullptr,
      nullptr, nullptr);
  // joint1: x_ring (f32 + bf16) and h2 in one pass over h1
  gemm256<7, false><<<dim3(8, 64), 512, 131072, stream>>>(
      h1, 1024, WtJ, 1024, fr_b2, c2, xrb, 1024, xring, Xb, nullptr, nullptr,
      nullptr);
  // w = softmax(h2 @ S^T + bc)
  centers_kernel<<<4096, 256, 0, stream>>>(Xb, S, bc, wtok);
  // joint2: gate -> d_out, fch -> h1 (w-corrections in epilogue)
  gemm256<8, false><<<dim3(8, 64), 512, 131072, stream>>>(
      xrb, 1024, WtG2, 1024, g_b, fc_b1, gate, 1024, h1, nullptr, wtok, G2T,
      F2T);
  // fc2 + final mix: out = gate*(fch @ fc_w2 + fc_b2) + (1-gate)*x_ring
  gemm256<4, false><<<dim3(4, 64), 512, 131072, stream>>>(
      h1, 1024, Wt6, 1024, fc_b2, nullptr, out, 1024, nullptr, nullptr, gate,
      xring, nullptr);
}